// Round 1
// baseline (12648.389 us; speedup 1.0000x reference)
//
#include <hip/hip_runtime.h>
#include <hip/hip_bf16.h>
#include <math.h>

#define S_LEN 1024
#define DIM   2048
#define NHQ   16
#define NHKV  4
#define HDIM  128
#define PDIM  8192
#define VOCAB 32000
#define NLAYER 4
#define NROWS (2 * S_LEN)   // B*S = 2048

typedef __attribute__((ext_vector_type(4))) float f32x4;
typedef __attribute__((ext_vector_type(8))) short bf16x8;

__device__ __forceinline__ void gload_lds16(const void* g, void* l) {
  __builtin_amdgcn_global_load_lds(
      (const __attribute__((address_space(1))) unsigned int*)g,
      (__attribute__((address_space(3))) unsigned int*)l, 16, 0, 0);
}

// ---------------- embedding gather (f32) ----------------
__global__ __launch_bounds__(256) void k_embed(const int* __restrict__ tokens,
    const float* __restrict__ emb, float* __restrict__ x) {
  int row = blockIdx.x;                    // b*S + s
  int tok = tokens[row];
  const f32x4* src = (const f32x4*)(emb + (size_t)tok * DIM);
  f32x4* dst = (f32x4*)(x + (size_t)row * DIM);
  for (int i = threadIdx.x; i < DIM / 4; i += 256) dst[i] = src[i];
}

// ---------------- rmsnorm f32 -> bf16 ----------------
__global__ __launch_bounds__(256) void k_rmsnorm(const float* __restrict__ x,
    const float* __restrict__ w, __hip_bfloat16* __restrict__ out) {
  int row = blockIdx.x;
  const float* xr = x + (size_t)row * DIM;
  float ss = 0.f;
  for (int i = threadIdx.x; i < DIM; i += 256) { float v = xr[i]; ss += v * v; }
  for (int off = 32; off; off >>= 1) ss += __shfl_xor(ss, off);
  __shared__ float wsum[4];
  if ((threadIdx.x & 63) == 0) wsum[threadIdx.x >> 6] = ss;
  __syncthreads();
  float tot = wsum[0] + wsum[1] + wsum[2] + wsum[3];
  float r = rsqrtf(tot / (float)DIM + 1e-5f);
  __hip_bfloat16* orow = out + (size_t)row * DIM;
  for (int i = threadIdx.x; i < DIM; i += 256)
    orow[i] = __float2bfloat16(w[i] * (xr[i] * r));
}

// ---------------- GEMM: A bf16 (MxK rm), B f32 weights (KxN rm), 128x128 tile ----------------
// EPI: 0 = store f32, 1 = add into f32, 2 = store bf16
template<int EPI>
__global__ __launch_bounds__(256) void k_gemm(
    const __hip_bfloat16* __restrict__ A, const float* __restrict__ Bw,
    void* __restrict__ Cv, int M, int N, int K) {
  __shared__ __hip_bfloat16 As[128][32];
  __shared__ __hip_bfloat16 Bs[128][40];   // [n][k], +8 pad keeps 16B alignment of rows
  int tid  = threadIdx.x;
  int bm = blockIdx.y * 128, bn = blockIdx.x * 128;
  int wave = tid >> 6, lane = tid & 63;
  int wr = (wave >> 1) * 64, wc = (wave & 1) * 64;
  int lrow = lane & 15, lk = (lane >> 4) * 8;
  f32x4 acc[4][4] = {};

  for (int k0 = 0; k0 < K; k0 += 32) {
    // A tile: 128x32 bf16 = 8KB -> 2x 16B loads/thread, linear LDS (lane-contiguous)
#pragma unroll
    for (int i = 0; i < 2; ++i) {
      int L = i * 256 + tid;
      int row = L >> 2, koff = (L & 3) * 8;
      gload_lds16(A + (size_t)(bm + row) * K + k0 + koff, &As[row][koff]);
    }
    // B tile: 32x128 f32, convert -> bf16, store transposed [n][k]
#pragma unroll
    for (int i = 0; i < 4; ++i) {
      int L = i * 256 + tid;          // 0..1023
      int kk = L >> 5;                // 0..31
      int c4 = (L & 31) * 4;          // 0..124
      f32x4 v = *(const f32x4*)(Bw + (size_t)(k0 + kk) * N + bn + c4);
#pragma unroll
      for (int j = 0; j < 4; ++j) Bs[c4 + j][kk] = __float2bfloat16(v[j]);
    }
    __syncthreads();
    bf16x8 af[4], bf[4];
#pragma unroll
    for (int mi = 0; mi < 4; ++mi)
      af[mi] = *(const bf16x8*)(&As[wr + mi * 16 + lrow][lk]);
#pragma unroll
    for (int ni = 0; ni < 4; ++ni)
      bf[ni] = *(const bf16x8*)(&Bs[wc + ni * 16 + lrow][lk]);
#pragma unroll
    for (int mi = 0; mi < 4; ++mi)
#pragma unroll
      for (int ni = 0; ni < 4; ++ni)
        acc[mi][ni] = __builtin_amdgcn_mfma_f32_16x16x32_bf16(af[mi], bf[ni], acc[mi][ni], 0, 0, 0);
    __syncthreads();
  }

  float* Cf = (float*)Cv;
  __hip_bfloat16* Cb = (__hip_bfloat16*)Cv;
#pragma unroll
  for (int mi = 0; mi < 4; ++mi)
#pragma unroll
    for (int ni = 0; ni < 4; ++ni)
#pragma unroll
      for (int r = 0; r < 4; ++r) {
        int row = bm + wr + mi * 16 + ((lane >> 4) * 4 + r);
        int col = bn + wc + ni * 16 + (lane & 15);
        size_t idx = (size_t)row * N + col;
        if (EPI == 0) Cf[idx] = acc[mi][ni][r];
        else if (EPI == 1) Cf[idx] += acc[mi][ni][r];
        else Cb[idx] = __float2bfloat16(acc[mi][ni][r]);
      }
}

// ---------------- RoPE + QKV split/reorder ----------------
// qkv f32 rows [b*S+s][3072]; writes q/k rope'd + v as bf16 [B][H][S][HD]
__global__ __launch_bounds__(256) void k_rope(const float* __restrict__ qkv,
    __hip_bfloat16* __restrict__ qr, __hip_bfloat16* __restrict__ kr,
    __hip_bfloat16* __restrict__ vr) {
  int rowid = blockIdx.x;                // b*S + s
  int b = rowid >> 10, s = rowid & (S_LEN - 1);
  const float* src = qkv + (size_t)rowid * 3072;
  const float kInvLog = 0.20503692777f;  // ln(500000)/64
  // Q: 16 heads x 64 pairs
  for (int it = threadIdx.x; it < NHQ * 64; it += 256) {
    int h = it >> 6, i = it & 63;
    float inv = expf(-(float)i * kInvLog);
    float ang = (float)s * inv;
    float sn, c; sincosf(ang, &sn, &c);
    float re = src[h * HDIM + i], im = src[h * HDIM + 64 + i];
    size_t dst = ((size_t)(b * NHQ + h) * S_LEN + s) * HDIM;
    qr[dst + 2 * i]     = __float2bfloat16(re * c - im * sn);
    qr[dst + 2 * i + 1] = __float2bfloat16(re * sn + im * c);
  }
  // K: 4 heads x 64 pairs
  for (int it = threadIdx.x; it < NHKV * 64; it += 256) {
    int h = it >> 6, i = it & 63;
    float inv = expf(-(float)i * kInvLog);
    float ang = (float)s * inv;
    float sn, c; sincosf(ang, &sn, &c);
    float re = src[DIM + h * HDIM + i], im = src[DIM + h * HDIM + 64 + i];
    size_t dst = ((size_t)(b * NHKV + h) * S_LEN + s) * HDIM;
    kr[dst + 2 * i]     = __float2bfloat16(re * c - im * sn);
    kr[dst + 2 * i + 1] = __float2bfloat16(re * sn + im * c);
  }
  // V: copy 4 heads x 128
  for (int it = threadIdx.x; it < NHKV * HDIM; it += 256) {
    int h = it >> 7, d = it & 127;
    size_t dst = ((size_t)(b * NHKV + h) * S_LEN + s) * HDIM + d;
    vr[dst] = __float2bfloat16(src[DIM + NHKV * HDIM + it]);
  }
}

// ---------------- causal attention, one wave per query row, online softmax ----------------
__global__ __launch_bounds__(256) void k_attn(
    const __hip_bfloat16* __restrict__ Q,   // [B][HQ][S][HD]
    const __hip_bfloat16* __restrict__ Kc,  // [B][HKV][S][HD]
    const __hip_bfloat16* __restrict__ Vc,  // [B][HKV][S][HD]
    __hip_bfloat16* __restrict__ O) {       // [B*S][2048], col = h*128+d
  int wave = threadIdx.x >> 6, lane = threadIdx.x & 63;
  int gw = blockIdx.x * 4 + wave;          // 0 .. B*HQ*S-1
  int qi = gw & (S_LEN - 1);
  int bh = gw >> 10;                       // b*HQ + h
  int b = bh >> 4, h = bh & 15;
  int hk = h >> 2;                         // RATIO = 4
  const __hip_bfloat16* qrow = Q + ((size_t)bh * S_LEN + qi) * HDIM;
  float q0 = __bfloat162float(qrow[lane]);
  float q1 = __bfloat162float(qrow[64 + lane]);
  const __hip_bfloat16* Kb = Kc + (size_t)(b * NHKV + hk) * S_LEN * HDIM;
  const __hip_bfloat16* Vb = Vc + (size_t)(b * NHKV + hk) * S_LEN * HDIM;
  const float scale = 0.08838834764831845f;  // 1/sqrt(128)
  float m = -INFINITY, lsum = 0.f, a0 = 0.f, a1 = 0.f;
  for (int kj = 0; kj <= qi; ++kj) {
    float d = q0 * __bfloat162float(Kb[kj * HDIM + lane]) +
              q1 * __bfloat162float(Kb[kj * HDIM + 64 + lane]);
    for (int off = 32; off; off >>= 1) d += __shfl_xor(d, off);
    d *= scale;
    float mn = fmaxf(m, d);
    float corr = __expf(m - mn);           // first iter: exp(-inf)=0
    float p = __expf(d - mn);
    lsum = lsum * corr + p;
    a0 = a0 * corr + p * __bfloat162float(Vb[kj * HDIM + lane]);
    a1 = a1 * corr + p * __bfloat162float(Vb[kj * HDIM + 64 + lane]);
    m = mn;
  }
  float inv = 1.f / lsum;
  __hip_bfloat16* orow = O + (size_t)(b * S_LEN + qi) * DIM + h * HDIM;
  orow[lane]      = __float2bfloat16(a0 * inv);
  orow[64 + lane] = __float2bfloat16(a1 * inv);
}

// ---------------- swiglu: h = silu(g) * u ----------------
__global__ __launch_bounds__(256) void k_swiglu(const __hip_bfloat16* __restrict__ gu,
    __hip_bfloat16* __restrict__ h) {
  size_t i = (size_t)blockIdx.x * 256 + threadIdx.x;  // over 2048*8192
  size_t row = i >> 13, col = i & (PDIM - 1);
  float g = __bfloat162float(gu[row * (2 * PDIM) + col]);
  float u = __bfloat162float(gu[row * (2 * PDIM) + PDIM + col]);
  float s = g / (1.f + __expf(-g));
  h[i] = __float2bfloat16(s * u);
}

extern "C" void kernel_launch(void* const* d_in, const int* in_sizes, int n_in,
                              void* d_out, int out_size, void* d_ws, size_t ws_size,
                              hipStream_t stream) {
  const int*   tokens    = (const int*)d_in[0];
  const float* emb       = (const float*)d_in[1];
  const float* w_qkv     = (const float*)d_in[2];
  const float* w_o       = (const float*)d_in[3];
  const float* w_gate_up = (const float*)d_in[4];
  const float* w_down    = (const float*)d_in[5];
  const float* ln_attn   = (const float*)d_in[6];
  const float* ln_ffn    = (const float*)d_in[7];
  const float* ln_f      = (const float*)d_in[8];
  const float* w_lm      = (const float*)d_in[9];
  float* out = (float*)d_out;

  char* ws = (char*)d_ws;
  float* x = (float*)ws;                    ws += (size_t)NROWS * DIM * 4;
  __hip_bfloat16* xn = (__hip_bfloat16*)ws; ws += (size_t)NROWS * DIM * 2;
  float* qkv = (float*)ws;                  ws += (size_t)NROWS * 3072 * 4;
  __hip_bfloat16* qr = (__hip_bfloat16*)ws; ws += (size_t)2 * NHQ * S_LEN * HDIM * 2;
  __hip_bfloat16* kr = (__hip_bfloat16*)ws; ws += (size_t)2 * NHKV * S_LEN * HDIM * 2;
  __hip_bfloat16* vr = (__hip_bfloat16*)ws; ws += (size_t)2 * NHKV * S_LEN * HDIM * 2;
  __hip_bfloat16* ao = (__hip_bfloat16*)ws; ws += (size_t)NROWS * DIM * 2;
  __hip_bfloat16* gu = (__hip_bfloat16*)ws; ws += (size_t)NROWS * 2 * PDIM * 2;
  __hip_bfloat16* hb = (__hip_bfloat16*)ws; ws += (size_t)NROWS * PDIM * 2;

  k_embed<<<NROWS, 256, 0, stream>>>(tokens, emb, x);

  for (int l = 0; l < NLAYER; ++l) {
    k_rmsnorm<<<NROWS, 256, 0, stream>>>(x, ln_attn + (size_t)l * DIM, xn);
    k_gemm<0><<<dim3(3072 / 128, NROWS / 128), 256, 0, stream>>>(
        xn, w_qkv + (size_t)l * DIM * 3072, qkv, NROWS, 3072, DIM);
    k_rope<<<NROWS, 256, 0, stream>>>(qkv, qr, kr, vr);
    k_attn<<<(2 * NHQ * S_LEN) / 4, 256, 0, stream>>>(qr, kr, vr, ao);
    k_gemm<1><<<dim3(DIM / 128, NROWS / 128), 256, 0, stream>>>(
        ao, w_o + (size_t)l * DIM * DIM, x, NROWS, DIM, DIM);
    k_rmsnorm<<<NROWS, 256, 0, stream>>>(x, ln_ffn + (size_t)l * DIM, xn);
    k_gemm<2><<<dim3(2 * PDIM / 128, NROWS / 128), 256, 0, stream>>>(
        xn, w_gate_up + (size_t)l * DIM * 2 * PDIM, gu, NROWS, 2 * PDIM, DIM);
    k_swiglu<<<(NROWS * PDIM) / 256, 256, 0, stream>>>(gu, hb);
    k_gemm<1><<<dim3(DIM / 128, NROWS / 128), 256, 0, stream>>>(
        hb, w_down + (size_t)l * PDIM * DIM, x, NROWS, DIM, PDIM);
  }

  k_rmsnorm<<<NROWS, 256, 0, stream>>>(x, ln_f, xn);
  k_gemm<0><<<dim3(VOCAB / 128, NROWS / 128), 256, 0, stream>>>(
      xn, w_lm, out, NROWS, VOCAB, DIM);
}

// Round 2
// 3341.345 us; speedup vs baseline: 3.7854x; 3.7854x over previous
//
#include <hip/hip_runtime.h>
#include <hip/hip_bf16.h>
#include <math.h>

#define S_LEN 1024
#define DIM   2048
#define NHQ   16
#define NHKV  4
#define HDIM  128
#define PDIM  8192
#define VOCAB 32000
#define NLAYER 4
#define NROWS (2 * S_LEN)   // B*S = 2048

typedef __attribute__((ext_vector_type(4))) float f32x4;
typedef __attribute__((ext_vector_type(8))) short bf16x8;

__device__ __forceinline__ void gload_lds16(const void* g, void* l) {
  __builtin_amdgcn_global_load_lds(
      (const __attribute__((address_space(1))) unsigned int*)g,
      (__attribute__((address_space(3))) unsigned int*)l, 16, 0, 0);
}

// ---------------- embedding gather (f32) ----------------
__global__ __launch_bounds__(256) void k_embed(const int* __restrict__ tokens,
    const float* __restrict__ emb, float* __restrict__ x) {
  int row = blockIdx.x;
  int tok = tokens[row];
  const f32x4* src = (const f32x4*)(emb + (size_t)tok * DIM);
  f32x4* dst = (f32x4*)(x + (size_t)row * DIM);
  for (int i = threadIdx.x; i < DIM / 4; i += 256) dst[i] = src[i];
}

// ---------------- rmsnorm f32 -> bf16 ----------------
__global__ __launch_bounds__(256) void k_rmsnorm(const float* __restrict__ x,
    const float* __restrict__ w, __hip_bfloat16* __restrict__ out) {
  int row = blockIdx.x;
  const float* xr = x + (size_t)row * DIM;
  float ss = 0.f;
  for (int i = threadIdx.x; i < DIM; i += 256) { float v = xr[i]; ss += v * v; }
  for (int off = 32; off; off >>= 1) ss += __shfl_xor(ss, off);
  __shared__ float wsum[4];
  if ((threadIdx.x & 63) == 0) wsum[threadIdx.x >> 6] = ss;
  __syncthreads();
  float tot = wsum[0] + wsum[1] + wsum[2] + wsum[3];
  float r = rsqrtf(tot / (float)DIM + 1e-5f);
  __hip_bfloat16* orow = out + (size_t)row * DIM;
  for (int i = threadIdx.x; i < DIM; i += 256)
    orow[i] = __float2bfloat16(w[i] * (xr[i] * r));
}

// ---------------- weight transpose+convert: W[K][N] f32 -> WT[N][K] bf16 ----------------
__global__ __launch_bounds__(256) void k_wt(const float* __restrict__ W,
    __hip_bfloat16* __restrict__ WT, int K, int N) {
  __shared__ __hip_bfloat16 t[64][72];   // [n][k], +8 pad
  int k0 = blockIdx.y * 64, n0 = blockIdx.x * 64;
  int r = threadIdx.x >> 4;          // 0..15
  int c4 = (threadIdx.x & 15) * 4;   // 0..60
#pragma unroll
  for (int i = 0; i < 4; ++i) {
    int k = r + i * 16;
    f32x4 v = *(const f32x4*)(W + (size_t)(k0 + k) * N + n0 + c4);
#pragma unroll
    for (int j = 0; j < 4; ++j) t[c4 + j][k] = __float2bfloat16(v[j]);
  }
  __syncthreads();
  int n = threadIdx.x >> 2, kc = (threadIdx.x & 3) * 16;
  bf16x8* dst = (bf16x8*)(WT + (size_t)(n0 + n) * K + k0 + kc);
  dst[0] = *(const bf16x8*)&t[n][kc];
  dst[1] = *(const bf16x8*)&t[n][kc + 8];
}

// ---------------- GEMM (m97 structure): A bf16 [M][K], BT bf16 [N][K] ----------------
// EPI: 0 = store f32, 1 = add into f32, 2 = store bf16
template<int EPI>
__global__ __launch_bounds__(256) void k_gemm_bt(
    const __hip_bfloat16* __restrict__ A, const __hip_bfloat16* __restrict__ BT,
    void* __restrict__ Cv, int M, int N, int K) {
  __shared__ __hip_bfloat16 As[128][32];
  __shared__ __hip_bfloat16 Bs[128][32];
  int tid  = threadIdx.x;
  int bm = blockIdx.y * 128, bn = blockIdx.x * 128;
  int wave = tid >> 6, lane = tid & 63;
  int wr = (wave >> 1) * 64, wc = (wave & 1) * 64;
  int lrow = lane & 15, lk = (lane >> 4) * 8;
  f32x4 acc[4][4] = {};

  for (int k0 = 0; k0 < K; k0 += 32) {
#pragma unroll
    for (int i = 0; i < 2; ++i) {
      int L = i * 256 + tid;
      int rw = L >> 2, kf = (L & 3) * 8;
      gload_lds16(A + (size_t)(bm + rw) * K + k0 + kf, &As[rw][kf]);
      gload_lds16(BT + (size_t)(bn + rw) * K + k0 + kf, &Bs[rw][kf]);
    }
    __syncthreads();
    bf16x8 af[4], bfr[4];
#pragma unroll
    for (int mi = 0; mi < 4; ++mi)
      af[mi] = *(const bf16x8*)(&As[wr + mi * 16 + lrow][lk]);
#pragma unroll
    for (int ni = 0; ni < 4; ++ni)
      bfr[ni] = *(const bf16x8*)(&Bs[wc + ni * 16 + lrow][lk]);
#pragma unroll
    for (int mi = 0; mi < 4; ++mi)
#pragma unroll
      for (int ni = 0; ni < 4; ++ni)
        acc[mi][ni] = __builtin_amdgcn_mfma_f32_16x16x32_bf16(af[mi], bfr[ni], acc[mi][ni], 0, 0, 0);
    __syncthreads();
  }

  float* Cf = (float*)Cv;
  __hip_bfloat16* Cb = (__hip_bfloat16*)Cv;
#pragma unroll
  for (int mi = 0; mi < 4; ++mi)
#pragma unroll
    for (int ni = 0; ni < 4; ++ni)
#pragma unroll
      for (int r = 0; r < 4; ++r) {
        int row = bm + wr + mi * 16 + ((lane >> 4) * 4 + r);
        int col = bn + wc + ni * 16 + (lane & 15);
        size_t idx = (size_t)row * N + col;
        if (EPI == 0) Cf[idx] = acc[mi][ni][r];
        else if (EPI == 1) Cf[idx] += acc[mi][ni][r];
        else Cb[idx] = __float2bfloat16(acc[mi][ni][r]);
      }
}

// ---------------- fallback GEMM: B from f32 weights (round-0 path) ----------------
template<int EPI>
__global__ __launch_bounds__(256) void k_gemm(
    const __hip_bfloat16* __restrict__ A, const float* __restrict__ Bw,
    void* __restrict__ Cv, int M, int N, int K) {
  __shared__ __hip_bfloat16 As[128][32];
  __shared__ __hip_bfloat16 Bs[128][40];
  int tid  = threadIdx.x;
  int bm = blockIdx.y * 128, bn = blockIdx.x * 128;
  int wave = tid >> 6, lane = tid & 63;
  int wr = (wave >> 1) * 64, wc = (wave & 1) * 64;
  int lrow = lane & 15, lk = (lane >> 4) * 8;
  f32x4 acc[4][4] = {};
  for (int k0 = 0; k0 < K; k0 += 32) {
#pragma unroll
    for (int i = 0; i < 2; ++i) {
      int L = i * 256 + tid;
      int row = L >> 2, koff = (L & 3) * 8;
      gload_lds16(A + (size_t)(bm + row) * K + k0 + koff, &As[row][koff]);
    }
#pragma unroll
    for (int i = 0; i < 4; ++i) {
      int L = i * 256 + tid;
      int kk = L >> 5;
      int c4 = (L & 31) * 4;
      f32x4 v = *(const f32x4*)(Bw + (size_t)(k0 + kk) * N + bn + c4);
#pragma unroll
      for (int j = 0; j < 4; ++j) Bs[c4 + j][kk] = __float2bfloat16(v[j]);
    }
    __syncthreads();
    bf16x8 af[4], bfr[4];
#pragma unroll
    for (int mi = 0; mi < 4; ++mi)
      af[mi] = *(const bf16x8*)(&As[wr + mi * 16 + lrow][lk]);
#pragma unroll
    for (int ni = 0; ni < 4; ++ni)
      bfr[ni] = *(const bf16x8*)(&Bs[wc + ni * 16 + lrow][lk]);
#pragma unroll
    for (int mi = 0; mi < 4; ++mi)
#pragma unroll
      for (int ni = 0; ni < 4; ++ni)
        acc[mi][ni] = __builtin_amdgcn_mfma_f32_16x16x32_bf16(af[mi], bfr[ni], acc[mi][ni], 0, 0, 0);
    __syncthreads();
  }
  float* Cf = (float*)Cv;
  __hip_bfloat16* Cb = (__hip_bfloat16*)Cv;
#pragma unroll
  for (int mi = 0; mi < 4; ++mi)
#pragma unroll
    for (int ni = 0; ni < 4; ++ni)
#pragma unroll
      for (int r = 0; r < 4; ++r) {
        int row = bm + wr + mi * 16 + ((lane >> 4) * 4 + r);
        int col = bn + wc + ni * 16 + (lane & 15);
        size_t idx = (size_t)row * N + col;
        if (EPI == 0) Cf[idx] = acc[mi][ni][r];
        else if (EPI == 1) Cf[idx] += acc[mi][ni][r];
        else Cb[idx] = __float2bfloat16(acc[mi][ni][r]);
      }
}

// ---------------- RoPE + QKV split/reorder (Q pre-scaled, V transposed) ----------------
__global__ __launch_bounds__(256) void k_rope(const float* __restrict__ qkv,
    __hip_bfloat16* __restrict__ qr, __hip_bfloat16* __restrict__ kr,
    __hip_bfloat16* __restrict__ vt) {
  int rowid = blockIdx.x;
  int b = rowid >> 10, s = rowid & (S_LEN - 1);
  const float* src = qkv + (size_t)rowid * 3072;
  const float kInvLog = 0.20503692777f;  // ln(500000)/64
  const float scale = 0.08838834764831845f;  // 1/sqrt(128)
  __shared__ float cs[64], sn[64];
  if (threadIdx.x < 64) {
    float inv = expf(-(float)threadIdx.x * kInvLog);
    float a = (float)s * inv;
    sincosf(a, &sn[threadIdx.x], &cs[threadIdx.x]);
  }
  __syncthreads();
  for (int it = threadIdx.x; it < NHQ * 64; it += 256) {
    int h = it >> 6, i = it & 63;
    float re = src[h * HDIM + i], im = src[h * HDIM + 64 + i];
    size_t dst = ((size_t)(b * NHQ + h) * S_LEN + s) * HDIM;
    qr[dst + 2 * i]     = __float2bfloat16((re * cs[i] - im * sn[i]) * scale);
    qr[dst + 2 * i + 1] = __float2bfloat16((re * sn[i] + im * cs[i]) * scale);
  }
  for (int it = threadIdx.x; it < NHKV * 64; it += 256) {
    int h = it >> 6, i = it & 63;
    float re = src[DIM + h * HDIM + i], im = src[DIM + h * HDIM + 64 + i];
    size_t dst = ((size_t)(b * NHKV + h) * S_LEN + s) * HDIM;
    kr[dst + 2 * i]     = __float2bfloat16(re * cs[i] - im * sn[i]);
    kr[dst + 2 * i + 1] = __float2bfloat16(re * sn[i] + im * cs[i]);
  }
  // V transposed: vt[b][hk][hd][s]
  for (int it = threadIdx.x; it < NHKV * HDIM; it += 256) {
    int h = it >> 7, d = it & 127;
    vt[(((size_t)b * NHKV + h) * HDIM + d) * S_LEN + s] =
        __float2bfloat16(src[DIM + NHKV * HDIM + it]);
  }
}

// ---------------- MFMA flash attention ----------------
// one wave = 16 q rows; kv tiles of 32; Q pre-scaled by 1/sqrt(HD)
__global__ __launch_bounds__(256) void k_attn_mfma(
    const __hip_bfloat16* __restrict__ Q,   // [B][HQ][S][HD]
    const __hip_bfloat16* __restrict__ Kc,  // [B][HKV][S][HD]
    const __hip_bfloat16* __restrict__ VT,  // [B][HKV][HD][S]
    __hip_bfloat16* __restrict__ O) {       // [B*S][2048], col = h*128+d
  __shared__ __hip_bfloat16 plds[4][16][40];
  int wave = threadIdx.x >> 6, lane = threadIdx.x & 63;
  int gw = blockIdx.x * 4 + wave;     // 0 .. B*HQ*(S/16)-1
  int qt = gw & 63;
  int bh = gw >> 6;                   // b*HQ + h
  int b = bh >> 4, h = bh & 15;
  int hk = h >> 2;
  int q0 = qt * 16;
  int g = lane >> 4, c = lane & 15;
  const __hip_bfloat16* Qb = Q + ((size_t)bh * S_LEN + q0) * HDIM;
  const __hip_bfloat16* Kb = Kc + (size_t)(b * NHKV + hk) * S_LEN * HDIM;
  const __hip_bfloat16* Vb = VT + (size_t)(b * NHKV + hk) * S_LEN * HDIM;

  bf16x8 qf[4];
#pragma unroll
  for (int cn = 0; cn < 4; ++cn)
    qf[cn] = *(const bf16x8*)(Qb + (size_t)c * HDIM + cn * 32 + g * 8);

  f32x4 po[8] = {};                    // po[t][r] = O[q0+g*4+r][t*16+c]
  float m[4], l[4];
#pragma unroll
  for (int r = 0; r < 4; ++r) { m[r] = -1e30f; l[r] = 0.f; }

  int kvend = q0 + 16;
  for (int kv0 = 0; kv0 < kvend; kv0 += 32) {
    f32x4 s0 = {}, s1 = {};
#pragma unroll
    for (int cn = 0; cn < 4; ++cn) {
      bf16x8 k0f = *(const bf16x8*)(Kb + (size_t)(kv0 + c) * HDIM + cn * 32 + g * 8);
      bf16x8 k1f = *(const bf16x8*)(Kb + (size_t)(kv0 + 16 + c) * HDIM + cn * 32 + g * 8);
      s0 = __builtin_amdgcn_mfma_f32_16x16x32_bf16(qf[cn], k0f, s0, 0, 0, 0);
      s1 = __builtin_amdgcn_mfma_f32_16x16x32_bf16(qf[cn], k1f, s1, 0, 0, 0);
    }
    if (kv0 + 31 > q0) {               // diagonal tile: causal mask
#pragma unroll
      for (int r = 0; r < 4; ++r) {
        int qrow = q0 + g * 4 + r;
        if (kv0 + c > qrow)      s0[r] = -1e30f;
        if (kv0 + 16 + c > qrow) s1[r] = -1e30f;
      }
    }
    float rm[4];
#pragma unroll
    for (int r = 0; r < 4; ++r) rm[r] = fmaxf(s0[r], s1[r]);
#pragma unroll
    for (int off = 1; off < 16; off <<= 1)
#pragma unroll
      for (int r = 0; r < 4; ++r) rm[r] = fmaxf(rm[r], __shfl_xor(rm[r], off));
    float p0[4], p1[4], rs[4];
#pragma unroll
    for (int r = 0; r < 4; ++r) {
      float mn = fmaxf(m[r], rm[r]);
      float corr = __expf(m[r] - mn);
      m[r] = mn;
      p0[r] = __expf(s0[r] - mn);
      p1[r] = __expf(s1[r] - mn);
      rs[r] = p0[r] + p1[r];
      l[r] *= corr;
#pragma unroll
      for (int t = 0; t < 8; ++t) po[t][r] *= corr;
    }
#pragma unroll
    for (int off = 1; off < 16; off <<= 1)
#pragma unroll
      for (int r = 0; r < 4; ++r) rs[r] += __shfl_xor(rs[r], off);
#pragma unroll
    for (int r = 0; r < 4; ++r) l[r] += rs[r];
    // P -> LDS (transpose to A-fragment layout), then P·V
#pragma unroll
    for (int r = 0; r < 4; ++r) {
      plds[wave][g * 4 + r][c]      = __float2bfloat16(p0[r]);
      plds[wave][g * 4 + r][16 + c] = __float2bfloat16(p1[r]);
    }
    bf16x8 pf = *(const bf16x8*)&plds[wave][c][g * 8];
#pragma unroll
    for (int t = 0; t < 8; ++t) {
      bf16x8 vf = *(const bf16x8*)(Vb + (size_t)(t * 16 + c) * S_LEN + kv0 + g * 8);
      po[t] = __builtin_amdgcn_mfma_f32_16x16x32_bf16(pf, vf, po[t], 0, 0, 0);
    }
  }
  float inv[4];
#pragma unroll
  for (int r = 0; r < 4; ++r) inv[r] = 1.f / l[r];
  __hip_bfloat16* ob = O + ((size_t)(b * S_LEN) + q0) * DIM + h * HDIM;
#pragma unroll
  for (int t = 0; t < 8; ++t)
#pragma unroll
    for (int r = 0; r < 4; ++r)
      ob[(size_t)(g * 4 + r) * DIM + t * 16 + c] = __float2bfloat16(po[t][r] * inv[r]);
}

// ---------------- swiglu ----------------
__global__ __launch_bounds__(256) void k_swiglu(const __hip_bfloat16* __restrict__ gu,
    __hip_bfloat16* __restrict__ h) {
  size_t i = (size_t)blockIdx.x * 256 + threadIdx.x;
  size_t row = i >> 13, col = i & (PDIM - 1);
  float g = __bfloat162float(gu[row * (2 * PDIM) + col]);
  float u = __bfloat162float(gu[row * (2 * PDIM) + PDIM + col]);
  float s = g / (1.f + __expf(-g));
  h[i] = __float2bfloat16(s * u);
}

extern "C" void kernel_launch(void* const* d_in, const int* in_sizes, int n_in,
                              void* d_out, int out_size, void* d_ws, size_t ws_size,
                              hipStream_t stream) {
  const int*   tokens    = (const int*)d_in[0];
  const float* emb       = (const float*)d_in[1];
  const float* w_qkv     = (const float*)d_in[2];
  const float* w_o       = (const float*)d_in[3];
  const float* w_gate_up = (const float*)d_in[4];
  const float* w_down    = (const float*)d_in[5];
  const float* ln_attn   = (const float*)d_in[6];
  const float* ln_ffn    = (const float*)d_in[7];
  const float* ln_f      = (const float*)d_in[8];
  const float* w_lm      = (const float*)d_in[9];
  float* out = (float*)d_out;

  char* ws = (char*)d_ws;
  float* x = (float*)ws;                    ws += (size_t)NROWS * DIM * 4;
  __hip_bfloat16* xn = (__hip_bfloat16*)ws; ws += (size_t)NROWS * DIM * 2;
  float* qkv = (float*)ws;                  ws += (size_t)NROWS * 3072 * 4;
  __hip_bfloat16* qr = (__hip_bfloat16*)ws; ws += (size_t)2 * NHQ * S_LEN * HDIM * 2;
  __hip_bfloat16* kr = (__hip_bfloat16*)ws; ws += (size_t)2 * NHKV * S_LEN * HDIM * 2;
  __hip_bfloat16* vt = (__hip_bfloat16*)ws; ws += (size_t)2 * NHKV * S_LEN * HDIM * 2;
  __hip_bfloat16* ao = (__hip_bfloat16*)ws; ws += (size_t)NROWS * DIM * 2;
  __hip_bfloat16* gu = (__hip_bfloat16*)ws; ws += (size_t)NROWS * 2 * PDIM * 2;
  __hip_bfloat16* hb = (__hip_bfloat16*)ws; ws += (size_t)NROWS * PDIM * 2;
  __hip_bfloat16* wbuf = (__hip_bfloat16*)ws;           // JIT bf16 W^T buffer
  size_t need = (size_t)(ws - (char*)d_ws) + (size_t)VOCAB * DIM * 2;
  bool bf16w = ws_size >= need;

  k_embed<<<NROWS, 256, 0, stream>>>(tokens, emb, x);

  for (int l = 0; l < NLAYER; ++l) {
    k_rmsnorm<<<NROWS, 256, 0, stream>>>(x, ln_attn + (size_t)l * DIM, xn);
    if (bf16w) {
      k_wt<<<dim3(3072 / 64, DIM / 64), 256, 0, stream>>>(
          w_qkv + (size_t)l * DIM * 3072, wbuf, DIM, 3072);
      k_gemm_bt<0><<<dim3(3072 / 128, NROWS / 128), 256, 0, stream>>>(
          xn, wbuf, qkv, NROWS, 3072, DIM);
    } else {
      k_gemm<0><<<dim3(3072 / 128, NROWS / 128), 256, 0, stream>>>(
          xn, w_qkv + (size_t)l * DIM * 3072, qkv, NROWS, 3072, DIM);
    }
    k_rope<<<NROWS, 256, 0, stream>>>(qkv, qr, kr, vt);
    k_attn_mfma<<<(2 * NHQ * (S_LEN / 16)) / 4, 256, 0, stream>>>(qr, kr, vt, ao);
    if (bf16w) {
      k_wt<<<dim3(DIM / 64, DIM / 64), 256, 0, stream>>>(
          w_o + (size_t)l * DIM * DIM, wbuf, DIM, DIM);
      k_gemm_bt<1><<<dim3(DIM / 128, NROWS / 128), 256, 0, stream>>>(
          ao, wbuf, x, NROWS, DIM, DIM);
    } else {
      k_gemm<1><<<dim3(DIM / 128, NROWS / 128), 256, 0, stream>>>(
          ao, w_o + (size_t)l * DIM * DIM, x, NROWS, DIM, DIM);
    }
    k_rmsnorm<<<NROWS, 256, 0, stream>>>(x, ln_ffn + (size_t)l * DIM, xn);
    if (bf16w) {
      k_wt<<<dim3(2 * PDIM / 64, DIM / 64), 256, 0, stream>>>(
          w_gate_up + (size_t)l * DIM * 2 * PDIM, wbuf, DIM, 2 * PDIM);
      k_gemm_bt<2><<<dim3(2 * PDIM / 128, NROWS / 128), 256, 0, stream>>>(
          xn, wbuf, gu, NROWS, 2 * PDIM, DIM);
    } else {
      k_gemm<2><<<dim3(2 * PDIM / 128, NROWS / 128), 256, 0, stream>>>(
          xn, w_gate_up + (size_t)l * DIM * 2 * PDIM, gu, NROWS, 2 * PDIM, DIM);
    }
    k_swiglu<<<(NROWS * PDIM) / 256, 256, 0, stream>>>(gu, hb);
    if (bf16w) {
      k_wt<<<dim3(DIM / 64, PDIM / 64), 256, 0, stream>>>(
          w_down + (size_t)l * PDIM * DIM, wbuf, PDIM, DIM);
      k_gemm_bt<1><<<dim3(DIM / 128, NROWS / 128), 256, 0, stream>>>(
          hb, wbuf, x, NROWS, DIM, PDIM);
    } else {
      k_gemm<1><<<dim3(DIM / 128, NROWS / 128), 256, 0, stream>>>(
          hb, w_down + (size_t)l * PDIM * DIM, x, NROWS, DIM, PDIM);
    }
  }

  k_rmsnorm<<<NROWS, 256, 0, stream>>>(x, ln_f, xn);
  if (bf16w) {
    k_wt<<<dim3(VOCAB / 64, DIM / 64), 256, 0, stream>>>(w_lm, wbuf, DIM, VOCAB);
    k_gemm_bt<0><<<dim3(VOCAB / 128, NROWS / 128), 256, 0, stream>>>(
        xn, wbuf, out, NROWS, VOCAB, DIM);
  } else {
    k_gemm<0><<<dim3(VOCAB / 128, NROWS / 128), 256, 0, stream>>>(
        xn, w_lm, out, NROWS, VOCAB, DIM);
  }
}

// Round 3
// 3339.380 us; speedup vs baseline: 3.7876x; 1.0006x over previous
//
#include <hip/hip_runtime.h>
#include <hip/hip_bf16.h>
#include <math.h>

#define S_LEN 1024
#define DIM   2048
#define NHQ   16
#define NHKV  4
#define HDIM  128
#define PDIM  8192
#define VOCAB 32000
#define NLAYER 4
#define NROWS (2 * S_LEN)   // B*S = 2048

typedef __attribute__((ext_vector_type(4))) float f32x4;
typedef __attribute__((ext_vector_type(8))) short bf16x8;

__device__ __forceinline__ void gload_lds16(const void* g, void* l) {
  __builtin_amdgcn_global_load_lds(
      (const __attribute__((address_space(1))) unsigned int*)g,
      (__attribute__((address_space(3))) unsigned int*)l, 16, 0, 0);
}

// ---------------- embedding gather (f32) ----------------
__global__ __launch_bounds__(256) void k_embed(const int* __restrict__ tokens,
    const float* __restrict__ emb, float* __restrict__ x) {
  int row = blockIdx.x;
  int tok = tokens[row];
  const f32x4* src = (const f32x4*)(emb + (size_t)tok * DIM);
  f32x4* dst = (f32x4*)(x + (size_t)row * DIM);
  for (int i = threadIdx.x; i < DIM / 4; i += 256) dst[i] = src[i];
}

// ---------------- rmsnorm f32 -> bf16 ----------------
__global__ __launch_bounds__(256) void k_rmsnorm(const float* __restrict__ x,
    const float* __restrict__ w, __hip_bfloat16* __restrict__ out) {
  int row = blockIdx.x;
  const float* xr = x + (size_t)row * DIM;
  float ss = 0.f;
  for (int i = threadIdx.x; i < DIM; i += 256) { float v = xr[i]; ss += v * v; }
  for (int off = 32; off; off >>= 1) ss += __shfl_xor(ss, off);
  __shared__ float wsum[4];
  if ((threadIdx.x & 63) == 0) wsum[threadIdx.x >> 6] = ss;
  __syncthreads();
  float tot = wsum[0] + wsum[1] + wsum[2] + wsum[3];
  float r = rsqrtf(tot / (float)DIM + 1e-5f);
  __hip_bfloat16* orow = out + (size_t)row * DIM;
  for (int i = threadIdx.x; i < DIM; i += 256)
    orow[i] = __float2bfloat16(w[i] * (xr[i] * r));
}

// ---------------- weight transpose+convert: W[K][N] f32 -> WT[N][K] bf16 ----------------
__global__ __launch_bounds__(256) void k_wt(const float* __restrict__ W,
    __hip_bfloat16* __restrict__ WT, int K, int N) {
  __shared__ __hip_bfloat16 t[64][72];   // [n][k], +8 pad
  int k0 = blockIdx.y * 64, n0 = blockIdx.x * 64;
  int r = threadIdx.x >> 4;          // 0..15
  int c4 = (threadIdx.x & 15) * 4;   // 0..60
#pragma unroll
  for (int i = 0; i < 4; ++i) {
    int k = r + i * 16;
    f32x4 v = *(const f32x4*)(W + (size_t)(k0 + k) * N + n0 + c4);
#pragma unroll
    for (int j = 0; j < 4; ++j) t[c4 + j][k] = __float2bfloat16(v[j]);
  }
  __syncthreads();
  int n = threadIdx.x >> 2, kc = (threadIdx.x & 3) * 16;
  bf16x8* dst = (bf16x8*)(WT + (size_t)(n0 + n) * K + k0 + kc);
  dst[0] = *(const bf16x8*)&t[n][kc];
  dst[1] = *(const bf16x8*)&t[n][kc + 8];
}

// ---------------- GEMM (m97 structure): A bf16 [M][K], BT bf16 [N][K] ----------------
// 1D grid, XCD-locality remap: each XCD owns 2 m-tile rows (A strip stays in
// its private L2), sweeps all n-tiles; (m,m+1) adjacent so a B panel is
// consumed by both while L2-hot. Requires M/128 == 16 (true for all calls).
// EPI: 0 = store f32, 1 = add into f32, 2 = store bf16
template<int EPI>
__global__ __launch_bounds__(256) void k_gemm_bt(
    const __hip_bfloat16* __restrict__ A, const __hip_bfloat16* __restrict__ BT,
    void* __restrict__ Cv, int M, int N, int K) {
  __shared__ __hip_bfloat16 As[128][32];
  __shared__ __hip_bfloat16 Bs[128][32];
  int nm = M >> 7, nn = N >> 7;
  int bid = blockIdx.x;
  int mt, nt;
  if (nm == 16) {
    int xcd = bid & 7;        // HW round-robins blocks across 8 XCDs
    int seq = bid >> 3;       // dispatch order within an XCD
    mt = (xcd << 1) | (seq & 1);
    nt = seq >> 1;
  } else {
    mt = bid % nm;            // column-major fallback
    nt = bid / nm;
  }
  int bm = mt << 7, bn = nt << 7;
  int tid  = threadIdx.x;
  int wave = tid >> 6, lane = tid & 63;
  int wr = (wave >> 1) * 64, wc = (wave & 1) * 64;
  int lrow = lane & 15, lk = (lane >> 4) * 8;
  f32x4 acc[4][4] = {};

  for (int k0 = 0; k0 < K; k0 += 32) {
#pragma unroll
    for (int i = 0; i < 2; ++i) {
      int L = i * 256 + tid;
      int rw = L >> 2, kf = (L & 3) * 8;
      gload_lds16(A + (size_t)(bm + rw) * K + k0 + kf, &As[rw][kf]);
      gload_lds16(BT + (size_t)(bn + rw) * K + k0 + kf, &Bs[rw][kf]);
    }
    __syncthreads();
    bf16x8 af[4], bfr[4];
#pragma unroll
    for (int mi = 0; mi < 4; ++mi)
      af[mi] = *(const bf16x8*)(&As[wr + mi * 16 + lrow][lk]);
#pragma unroll
    for (int ni = 0; ni < 4; ++ni)
      bfr[ni] = *(const bf16x8*)(&Bs[wc + ni * 16 + lrow][lk]);
#pragma unroll
    for (int mi = 0; mi < 4; ++mi)
#pragma unroll
      for (int ni = 0; ni < 4; ++ni)
        acc[mi][ni] = __builtin_amdgcn_mfma_f32_16x16x32_bf16(af[mi], bfr[ni], acc[mi][ni], 0, 0, 0);
    __syncthreads();
  }

  float* Cf = (float*)Cv;
  __hip_bfloat16* Cb = (__hip_bfloat16*)Cv;
#pragma unroll
  for (int mi = 0; mi < 4; ++mi)
#pragma unroll
    for (int ni = 0; ni < 4; ++ni)
#pragma unroll
      for (int r = 0; r < 4; ++r) {
        int row = bm + wr + mi * 16 + ((lane >> 4) * 4 + r);
        int col = bn + wc + ni * 16 + (lane & 15);
        size_t idx = (size_t)row * N + col;
        if (EPI == 0) Cf[idx] = acc[mi][ni][r];
        else if (EPI == 1) Cf[idx] += acc[mi][ni][r];
        else Cb[idx] = __float2bfloat16(acc[mi][ni][r]);
      }
}

// ---------------- fallback GEMM: B from f32 weights (round-0 path) ----------------
template<int EPI>
__global__ __launch_bounds__(256) void k_gemm(
    const __hip_bfloat16* __restrict__ A, const float* __restrict__ Bw,
    void* __restrict__ Cv, int M, int N, int K) {
  __shared__ __hip_bfloat16 As[128][32];
  __shared__ __hip_bfloat16 Bs[128][40];
  int tid  = threadIdx.x;
  int bm = blockIdx.y * 128, bn = blockIdx.x * 128;
  int wave = tid >> 6, lane = tid & 63;
  int wr = (wave >> 1) * 64, wc = (wave & 1) * 64;
  int lrow = lane & 15, lk = (lane >> 4) * 8;
  f32x4 acc[4][4] = {};
  for (int k0 = 0; k0 < K; k0 += 32) {
#pragma unroll
    for (int i = 0; i < 2; ++i) {
      int L = i * 256 + tid;
      int row = L >> 2, koff = (L & 3) * 8;
      gload_lds16(A + (size_t)(bm + row) * K + k0 + koff, &As[row][koff]);
    }
#pragma unroll
    for (int i = 0; i < 4; ++i) {
      int L = i * 256 + tid;
      int kk = L >> 5;
      int c4 = (L & 31) * 4;
      f32x4 v = *(const f32x4*)(Bw + (size_t)(k0 + kk) * N + bn + c4);
#pragma unroll
      for (int j = 0; j < 4; ++j) Bs[c4 + j][kk] = __float2bfloat16(v[j]);
    }
    __syncthreads();
    bf16x8 af[4], bfr[4];
#pragma unroll
    for (int mi = 0; mi < 4; ++mi)
      af[mi] = *(const bf16x8*)(&As[wr + mi * 16 + lrow][lk]);
#pragma unroll
    for (int ni = 0; ni < 4; ++ni)
      bfr[ni] = *(const bf16x8*)(&Bs[wc + ni * 16 + lrow][lk]);
#pragma unroll
    for (int mi = 0; mi < 4; ++mi)
#pragma unroll
      for (int ni = 0; ni < 4; ++ni)
        acc[mi][ni] = __builtin_amdgcn_mfma_f32_16x16x32_bf16(af[mi], bfr[ni], acc[mi][ni], 0, 0, 0);
    __syncthreads();
  }
  float* Cf = (float*)Cv;
  __hip_bfloat16* Cb = (__hip_bfloat16*)Cv;
#pragma unroll
  for (int mi = 0; mi < 4; ++mi)
#pragma unroll
    for (int ni = 0; ni < 4; ++ni)
#pragma unroll
      for (int r = 0; r < 4; ++r) {
        int row = bm + wr + mi * 16 + ((lane >> 4) * 4 + r);
        int col = bn + wc + ni * 16 + (lane & 15);
        size_t idx = (size_t)row * N + col;
        if (EPI == 0) Cf[idx] = acc[mi][ni][r];
        else if (EPI == 1) Cf[idx] += acc[mi][ni][r];
        else Cb[idx] = __float2bfloat16(acc[mi][ni][r]);
      }
}

// ---------------- RoPE + QKV split/reorder (Q pre-scaled, V transposed) ----------------
__global__ __launch_bounds__(256) void k_rope(const float* __restrict__ qkv,
    __hip_bfloat16* __restrict__ qr, __hip_bfloat16* __restrict__ kr,
    __hip_bfloat16* __restrict__ vt) {
  int rowid = blockIdx.x;
  int b = rowid >> 10, s = rowid & (S_LEN - 1);
  const float* src = qkv + (size_t)rowid * 3072;
  const float kInvLog = 0.20503692777f;  // ln(500000)/64
  const float scale = 0.08838834764831845f;  // 1/sqrt(128)
  __shared__ float cs[64], sn[64];
  if (threadIdx.x < 64) {
    float inv = expf(-(float)threadIdx.x * kInvLog);
    float a = (float)s * inv;
    sincosf(a, &sn[threadIdx.x], &cs[threadIdx.x]);
  }
  __syncthreads();
  for (int it = threadIdx.x; it < NHQ * 64; it += 256) {
    int h = it >> 6, i = it & 63;
    float re = src[h * HDIM + i], im = src[h * HDIM + 64 + i];
    size_t dst = ((size_t)(b * NHQ + h) * S_LEN + s) * HDIM;
    qr[dst + 2 * i]     = __float2bfloat16((re * cs[i] - im * sn[i]) * scale);
    qr[dst + 2 * i + 1] = __float2bfloat16((re * sn[i] + im * cs[i]) * scale);
  }
  for (int it = threadIdx.x; it < NHKV * 64; it += 256) {
    int h = it >> 6, i = it & 63;
    float re = src[DIM + h * HDIM + i], im = src[DIM + h * HDIM + 64 + i];
    size_t dst = ((size_t)(b * NHKV + h) * S_LEN + s) * HDIM;
    kr[dst + 2 * i]     = __float2bfloat16(re * cs[i] - im * sn[i]);
    kr[dst + 2 * i + 1] = __float2bfloat16(re * sn[i] + im * cs[i]);
  }
  // V transposed: vt[b][hk][hd][s]
  for (int it = threadIdx.x; it < NHKV * HDIM; it += 256) {
    int h = it >> 7, d = it & 127;
    vt[(((size_t)b * NHKV + h) * HDIM + d) * S_LEN + s] =
        __float2bfloat16(src[DIM + NHKV * HDIM + it]);
  }
}

// ---------------- MFMA flash attention ----------------
__global__ __launch_bounds__(256) void k_attn_mfma(
    const __hip_bfloat16* __restrict__ Q,   // [B][HQ][S][HD]
    const __hip_bfloat16* __restrict__ Kc,  // [B][HKV][S][HD]
    const __hip_bfloat16* __restrict__ VT,  // [B][HKV][HD][S]
    __hip_bfloat16* __restrict__ O) {       // [B*S][2048], col = h*128+d
  __shared__ __hip_bfloat16 plds[4][16][40];
  int wave = threadIdx.x >> 6, lane = threadIdx.x & 63;
  int gw = blockIdx.x * 4 + wave;     // 0 .. B*HQ*(S/16)-1
  int qt = gw & 63;
  int bh = gw >> 6;                   // b*HQ + h
  int b = bh >> 4, h = bh & 15;
  int hk = h >> 2;
  int q0 = qt * 16;
  int g = lane >> 4, c = lane & 15;
  const __hip_bfloat16* Qb = Q + ((size_t)bh * S_LEN + q0) * HDIM;
  const __hip_bfloat16* Kb = Kc + (size_t)(b * NHKV + hk) * S_LEN * HDIM;
  const __hip_bfloat16* Vb = VT + (size_t)(b * NHKV + hk) * S_LEN * HDIM;

  bf16x8 qf[4];
#pragma unroll
  for (int cn = 0; cn < 4; ++cn)
    qf[cn] = *(const bf16x8*)(Qb + (size_t)c * HDIM + cn * 32 + g * 8);

  f32x4 po[8] = {};
  float m[4], l[4];
#pragma unroll
  for (int r = 0; r < 4; ++r) { m[r] = -1e30f; l[r] = 0.f; }

  int kvend = q0 + 16;
  for (int kv0 = 0; kv0 < kvend; kv0 += 32) {
    f32x4 s0 = {}, s1 = {};
#pragma unroll
    for (int cn = 0; cn < 4; ++cn) {
      bf16x8 k0f = *(const bf16x8*)(Kb + (size_t)(kv0 + c) * HDIM + cn * 32 + g * 8);
      bf16x8 k1f = *(const bf16x8*)(Kb + (size_t)(kv0 + 16 + c) * HDIM + cn * 32 + g * 8);
      s0 = __builtin_amdgcn_mfma_f32_16x16x32_bf16(qf[cn], k0f, s0, 0, 0, 0);
      s1 = __builtin_amdgcn_mfma_f32_16x16x32_bf16(qf[cn], k1f, s1, 0, 0, 0);
    }
    if (kv0 + 31 > q0) {
#pragma unroll
      for (int r = 0; r < 4; ++r) {
        int qrow = q0 + g * 4 + r;
        if (kv0 + c > qrow)      s0[r] = -1e30f;
        if (kv0 + 16 + c > qrow) s1[r] = -1e30f;
      }
    }
    float rm[4];
#pragma unroll
    for (int r = 0; r < 4; ++r) rm[r] = fmaxf(s0[r], s1[r]);
#pragma unroll
    for (int off = 1; off < 16; off <<= 1)
#pragma unroll
      for (int r = 0; r < 4; ++r) rm[r] = fmaxf(rm[r], __shfl_xor(rm[r], off));
    float p0[4], p1[4], rs[4];
#pragma unroll
    for (int r = 0; r < 4; ++r) {
      float mn = fmaxf(m[r], rm[r]);
      float corr = __expf(m[r] - mn);
      m[r] = mn;
      p0[r] = __expf(s0[r] - mn);
      p1[r] = __expf(s1[r] - mn);
      rs[r] = p0[r] + p1[r];
      l[r] *= corr;
#pragma unroll
      for (int t = 0; t < 8; ++t) po[t][r] *= corr;
    }
#pragma unroll
    for (int off = 1; off < 16; off <<= 1)
#pragma unroll
      for (int r = 0; r < 4; ++r) rs[r] += __shfl_xor(rs[r], off);
#pragma unroll
    for (int r = 0; r < 4; ++r) l[r] += rs[r];
#pragma unroll
    for (int r = 0; r < 4; ++r) {
      plds[wave][g * 4 + r][c]      = __float2bfloat16(p0[r]);
      plds[wave][g * 4 + r][16 + c] = __float2bfloat16(p1[r]);
    }
    bf16x8 pf = *(const bf16x8*)&plds[wave][c][g * 8];
#pragma unroll
    for (int t = 0; t < 8; ++t) {
      bf16x8 vf = *(const bf16x8*)(Vb + (size_t)(t * 16 + c) * S_LEN + kv0 + g * 8);
      po[t] = __builtin_amdgcn_mfma_f32_16x16x32_bf16(pf, vf, po[t], 0, 0, 0);
    }
  }
  float inv[4];
#pragma unroll
  for (int r = 0; r < 4; ++r) inv[r] = 1.f / l[r];
  __hip_bfloat16* ob = O + ((size_t)(b * S_LEN) + q0) * DIM + h * HDIM;
#pragma unroll
  for (int t = 0; t < 8; ++t)
#pragma unroll
    for (int r = 0; r < 4; ++r)
      ob[(size_t)(g * 4 + r) * DIM + t * 16 + c] = __float2bfloat16(po[t][r] * inv[r]);
}

// ---------------- swiglu ----------------
__global__ __launch_bounds__(256) void k_swiglu(const __hip_bfloat16* __restrict__ gu,
    __hip_bfloat16* __restrict__ h) {
  size_t i = (size_t)blockIdx.x * 256 + threadIdx.x;
  size_t row = i >> 13, col = i & (PDIM - 1);
  float g = __bfloat162float(gu[row * (2 * PDIM) + col]);
  float u = __bfloat162float(gu[row * (2 * PDIM) + PDIM + col]);
  float s = g / (1.f + __expf(-g));
  h[i] = __float2bfloat16(s * u);
}

extern "C" void kernel_launch(void* const* d_in, const int* in_sizes, int n_in,
                              void* d_out, int out_size, void* d_ws, size_t ws_size,
                              hipStream_t stream) {
  const int*   tokens    = (const int*)d_in[0];
  const float* emb       = (const float*)d_in[1];
  const float* w_qkv     = (const float*)d_in[2];
  const float* w_o       = (const float*)d_in[3];
  const float* w_gate_up = (const float*)d_in[4];
  const float* w_down    = (const float*)d_in[5];
  const float* ln_attn   = (const float*)d_in[6];
  const float* ln_ffn    = (const float*)d_in[7];
  const float* ln_f      = (const float*)d_in[8];
  const float* w_lm      = (const float*)d_in[9];
  float* out = (float*)d_out;

  char* ws = (char*)d_ws;
  float* x = (float*)ws;                    ws += (size_t)NROWS * DIM * 4;
  __hip_bfloat16* xn = (__hip_bfloat16*)ws; ws += (size_t)NROWS * DIM * 2;
  float* qkv = (float*)ws;                  ws += (size_t)NROWS * 3072 * 4;
  __hip_bfloat16* qr = (__hip_bfloat16*)ws; ws += (size_t)2 * NHQ * S_LEN * HDIM * 2;
  __hip_bfloat16* kr = (__hip_bfloat16*)ws; ws += (size_t)2 * NHKV * S_LEN * HDIM * 2;
  __hip_bfloat16* vt = (__hip_bfloat16*)ws; ws += (size_t)2 * NHKV * S_LEN * HDIM * 2;
  __hip_bfloat16* ao = (__hip_bfloat16*)ws; ws += (size_t)NROWS * DIM * 2;
  __hip_bfloat16* gu = (__hip_bfloat16*)ws; ws += (size_t)NROWS * 2 * PDIM * 2;
  __hip_bfloat16* hb = (__hip_bfloat16*)ws; ws += (size_t)NROWS * PDIM * 2;
  __hip_bfloat16* wbuf = (__hip_bfloat16*)ws;           // JIT bf16 W^T buffer
  size_t need = (size_t)(ws - (char*)d_ws) + (size_t)VOCAB * DIM * 2;
  bool bf16w = ws_size >= need;

  k_embed<<<NROWS, 256, 0, stream>>>(tokens, emb, x);

  for (int l = 0; l < NLAYER; ++l) {
    k_rmsnorm<<<NROWS, 256, 0, stream>>>(x, ln_attn + (size_t)l * DIM, xn);
    if (bf16w) {
      k_wt<<<dim3(3072 / 64, DIM / 64), 256, 0, stream>>>(
          w_qkv + (size_t)l * DIM * 3072, wbuf, DIM, 3072);
      k_gemm_bt<0><<<(NROWS / 128) * (3072 / 128), 256, 0, stream>>>(
          xn, wbuf, qkv, NROWS, 3072, DIM);
    } else {
      k_gemm<0><<<dim3(3072 / 128, NROWS / 128), 256, 0, stream>>>(
          xn, w_qkv + (size_t)l * DIM * 3072, qkv, NROWS, 3072, DIM);
    }
    k_rope<<<NROWS, 256, 0, stream>>>(qkv, qr, kr, vt);
    k_attn_mfma<<<(2 * NHQ * (S_LEN / 16)) / 4, 256, 0, stream>>>(qr, kr, vt, ao);
    if (bf16w) {
      k_wt<<<dim3(DIM / 64, DIM / 64), 256, 0, stream>>>(
          w_o + (size_t)l * DIM * DIM, wbuf, DIM, DIM);
      k_gemm_bt<1><<<(NROWS / 128) * (DIM / 128), 256, 0, stream>>>(
          ao, wbuf, x, NROWS, DIM, DIM);
    } else {
      k_gemm<1><<<dim3(DIM / 128, NROWS / 128), 256, 0, stream>>>(
          ao, w_o + (size_t)l * DIM * DIM, x, NROWS, DIM, DIM);
    }
    k_rmsnorm<<<NROWS, 256, 0, stream>>>(x, ln_ffn + (size_t)l * DIM, xn);
    if (bf16w) {
      k_wt<<<dim3(2 * PDIM / 64, DIM / 64), 256, 0, stream>>>(
          w_gate_up + (size_t)l * DIM * 2 * PDIM, wbuf, DIM, 2 * PDIM);
      k_gemm_bt<2><<<(NROWS / 128) * (2 * PDIM / 128), 256, 0, stream>>>(
          xn, wbuf, gu, NROWS, 2 * PDIM, DIM);
    } else {
      k_gemm<2><<<dim3(2 * PDIM / 128, NROWS / 128), 256, 0, stream>>>(
          xn, w_gate_up + (size_t)l * DIM * 2 * PDIM, gu, NROWS, 2 * PDIM, DIM);
    }
    k_swiglu<<<(NROWS * PDIM) / 256, 256, 0, stream>>>(gu, hb);
    if (bf16w) {
      k_wt<<<dim3(DIM / 64, PDIM / 64), 256, 0, stream>>>(
          w_down + (size_t)l * PDIM * DIM, wbuf, PDIM, DIM);
      k_gemm_bt<1><<<(NROWS / 128) * (DIM / 128), 256, 0, stream>>>(
          hb, wbuf, x, NROWS, DIM, PDIM);
    } else {
      k_gemm<1><<<dim3(DIM / 128, NROWS / 128), 256, 0, stream>>>(
          hb, w_down + (size_t)l * PDIM * DIM, x, NROWS, DIM, PDIM);
    }
  }

  k_rmsnorm<<<NROWS, 256, 0, stream>>>(x, ln_f, xn);
  if (bf16w) {
    k_wt<<<dim3(VOCAB / 64, DIM / 64), 256, 0, stream>>>(w_lm, wbuf, DIM, VOCAB);
    k_gemm_bt<0><<<(NROWS / 128) * (VOCAB / 128), 256, 0, stream>>>(
        xn, wbuf, out, NROWS, VOCAB, DIM);
  } else {
    k_gemm<0><<<dim3(VOCAB / 128, NROWS / 128), 256, 0, stream>>>(
        xn, w_lm, out, NROWS, VOCAB, DIM);
  }
}

// Round 4
// 3058.462 us; speedup vs baseline: 4.1355x; 1.0918x over previous
//
#include <hip/hip_runtime.h>
#include <hip/hip_bf16.h>
#include <math.h>

#define S_LEN 1024
#define DIM   2048
#define NHQ   16
#define NHKV  4
#define HDIM  128
#define PDIM  8192
#define VOCAB 32000
#define NLAYER 4
#define NROWS (2 * S_LEN)   // B*S = 2048

typedef __attribute__((ext_vector_type(4))) float f32x4;
typedef __attribute__((ext_vector_type(8))) short bf16x8;

__device__ __forceinline__ void gload_lds16(const void* g, void* l) {
  __builtin_amdgcn_global_load_lds(
      (const __attribute__((address_space(1))) unsigned int*)g,
      (__attribute__((address_space(3))) unsigned int*)l, 16, 0, 0);
}

// ---------------- embedding gather (f32) ----------------
__global__ __launch_bounds__(256) void k_embed(const int* __restrict__ tokens,
    const float* __restrict__ emb, float* __restrict__ x) {
  int row = blockIdx.x;
  int tok = tokens[row];
  const f32x4* src = (const f32x4*)(emb + (size_t)tok * DIM);
  f32x4* dst = (f32x4*)(x + (size_t)row * DIM);
  for (int i = threadIdx.x; i < DIM / 4; i += 256) dst[i] = src[i];
}

// ---------------- rmsnorm f32 -> bf16 ----------------
__global__ __launch_bounds__(256) void k_rmsnorm(const float* __restrict__ x,
    const float* __restrict__ w, __hip_bfloat16* __restrict__ out) {
  int row = blockIdx.x;
  const float* xr = x + (size_t)row * DIM;
  float ss = 0.f;
  for (int i = threadIdx.x; i < DIM; i += 256) { float v = xr[i]; ss += v * v; }
  for (int off = 32; off; off >>= 1) ss += __shfl_xor(ss, off);
  __shared__ float wsum[4];
  if ((threadIdx.x & 63) == 0) wsum[threadIdx.x >> 6] = ss;
  __syncthreads();
  float tot = wsum[0] + wsum[1] + wsum[2] + wsum[3];
  float r = rsqrtf(tot / (float)DIM + 1e-5f);
  __hip_bfloat16* orow = out + (size_t)row * DIM;
  for (int i = threadIdx.x; i < DIM; i += 256)
    orow[i] = __float2bfloat16(w[i] * (xr[i] * r));
}

// ---------------- weight transpose+convert: W[K][N] f32 -> WT[N][K] bf16 ----------------
__global__ __launch_bounds__(256) void k_wt(const float* __restrict__ W,
    __hip_bfloat16* __restrict__ WT, int K, int N) {
  __shared__ __hip_bfloat16 t[64][72];   // [n][k], +8 pad
  int k0 = blockIdx.y * 64, n0 = blockIdx.x * 64;
  int r = threadIdx.x >> 4;          // 0..15
  int c4 = (threadIdx.x & 15) * 4;   // 0..60
#pragma unroll
  for (int i = 0; i < 4; ++i) {
    int k = r + i * 16;
    f32x4 v = *(const f32x4*)(W + (size_t)(k0 + k) * N + n0 + c4);
#pragma unroll
    for (int j = 0; j < 4; ++j) t[c4 + j][k] = __float2bfloat16(v[j]);
  }
  __syncthreads();
  int n = threadIdx.x >> 2, kc = (threadIdx.x & 3) * 16;
  bf16x8* dst = (bf16x8*)(WT + (size_t)(n0 + n) * K + k0 + kc);
  dst[0] = *(const bf16x8*)&t[n][kc];
  dst[1] = *(const bf16x8*)&t[n][kc + 8];
}

// ---------------- big GEMM: 256x256 tile, BK=64, 8 waves, dbuf LDS, XOR swizzle ----------------
// A bf16 [M][K], BT bf16 [N][K]. Requires M==2048 (8 m-tiles -> 1 per XCD) and N%256==0.
// EPI: 0 = store f32, 1 = add into f32, 2 = store bf16
template<int EPI>
__global__ __launch_bounds__(512) void k_gemm256(
    const __hip_bfloat16* __restrict__ A, const __hip_bfloat16* __restrict__ BT,
    void* __restrict__ Cv, int M, int N, int K) {
  __shared__ __hip_bfloat16 As[2][256][64];   // 64 KiB
  __shared__ __hip_bfloat16 Bs[2][256][64];   // 64 KiB
  int tid = threadIdx.x;
  int bid = blockIdx.x;
  int mt = bid & 7, nt = bid >> 3;   // XCD x owns m-strip x, sweeps n
  int bm = mt << 8, bn = nt << 8;
  int wave = tid >> 6, lane = tid & 63;
  int wm = wave >> 2, wn = wave & 3;           // 2x4 wave grid
  int g = lane >> 4, c = lane & 15;
  f32x4 acc[8][4] = {};

  // stage one 256x64 K-tile of A and B into buf. Physical LDS chunk (row, pc)
  // holds logical k-chunk pc ^ (row&7)  (inverse-swizzled global source,
  // linear lane-contiguous LDS dest — rule: both-sides-or-neither).
  auto stage = [&](int buf, int k0) {
#pragma unroll
    for (int i = 0; i < 4; ++i) {
      int ci = i * 512 + tid;          // 0..2047 chunk id, lane-contiguous
      int row = ci >> 3, pc = ci & 7;
      int jl = pc ^ (row & 7);
      gload_lds16(A + (size_t)(bm + row) * K + k0 + jl * 8, &As[buf][row][pc * 8]);
      gload_lds16(BT + (size_t)(bn + row) * K + k0 + jl * 8, &Bs[buf][row][pc * 8]);
    }
  };

  stage(0, 0);
  __syncthreads();                     // prologue drain (vmcnt 0)
  int ntiles = K >> 6;
  for (int t = 0; t < ntiles; ++t) {
    int cur = t & 1;
    if (t + 1 < ntiles) stage(cur ^ 1, (t + 1) << 6);   // prefetch next K-tile
#pragma unroll
    for (int kk = 0; kk < 2; ++kk) {
      bf16x8 af[8], bv[4];
#pragma unroll
      for (int mi = 0; mi < 8; ++mi) {
        int row = wm * 128 + mi * 16 + c;
        int ch = (kk * 4 + g) ^ (row & 7);
        af[mi] = *(const bf16x8*)&As[cur][row][ch * 8];
      }
#pragma unroll
      for (int ni = 0; ni < 4; ++ni) {
        int row = wn * 64 + ni * 16 + c;
        int ch = (kk * 4 + g) ^ (row & 7);
        bv[ni] = *(const bf16x8*)&Bs[cur][row][ch * 8];
      }
#pragma unroll
      for (int mi = 0; mi < 8; ++mi)
#pragma unroll
        for (int ni = 0; ni < 4; ++ni)
          acc[mi][ni] = __builtin_amdgcn_mfma_f32_16x16x32_bf16(af[mi], bv[ni], acc[mi][ni], 0, 0, 0);
    }
    __syncthreads();                   // drains vmcnt(0)+lgkmcnt(0): next tile staged, buf safe
  }

  float* Cf = (float*)Cv;
  __hip_bfloat16* Cb = (__hip_bfloat16*)Cv;
  int row0 = bm + wm * 128, col0 = bn + wn * 64;
#pragma unroll
  for (int mi = 0; mi < 8; ++mi)
#pragma unroll
    for (int ni = 0; ni < 4; ++ni)
#pragma unroll
      for (int r = 0; r < 4; ++r) {
        int row = row0 + mi * 16 + g * 4 + r;
        int col = col0 + ni * 16 + c;
        size_t idx = (size_t)row * N + col;
        if (EPI == 0) Cf[idx] = acc[mi][ni][r];
        else if (EPI == 1) Cf[idx] += acc[mi][ni][r];
        else Cb[idx] = __float2bfloat16(acc[mi][ni][r]);
      }
}

// ---------------- GEMM (m97 structure): A bf16 [M][K], BT bf16 [N][K], 128x128 ----------------
template<int EPI>
__global__ __launch_bounds__(256) void k_gemm_bt(
    const __hip_bfloat16* __restrict__ A, const __hip_bfloat16* __restrict__ BT,
    void* __restrict__ Cv, int M, int N, int K) {
  __shared__ __hip_bfloat16 As[128][32];
  __shared__ __hip_bfloat16 Bs[128][32];
  int nm = M >> 7, nn = N >> 7;
  int bid = blockIdx.x;
  int mt, nt;
  if (nm == 16) {
    int xcd = bid & 7;
    int seq = bid >> 3;
    mt = (xcd << 1) | (seq & 1);
    nt = seq >> 1;
  } else {
    mt = bid % nm;
    nt = bid / nm;
  }
  int bm = mt << 7, bn = nt << 7;
  int tid  = threadIdx.x;
  int wave = tid >> 6, lane = tid & 63;
  int wr = (wave >> 1) * 64, wc = (wave & 1) * 64;
  int lrow = lane & 15, lk = (lane >> 4) * 8;
  f32x4 acc[4][4] = {};

  for (int k0 = 0; k0 < K; k0 += 32) {
#pragma unroll
    for (int i = 0; i < 2; ++i) {
      int L = i * 256 + tid;
      int rw = L >> 2, kf = (L & 3) * 8;
      gload_lds16(A + (size_t)(bm + rw) * K + k0 + kf, &As[rw][kf]);
      gload_lds16(BT + (size_t)(bn + rw) * K + k0 + kf, &Bs[rw][kf]);
    }
    __syncthreads();
    bf16x8 af[4], bfr[4];
#pragma unroll
    for (int mi = 0; mi < 4; ++mi)
      af[mi] = *(const bf16x8*)(&As[wr + mi * 16 + lrow][lk]);
#pragma unroll
    for (int ni = 0; ni < 4; ++ni)
      bfr[ni] = *(const bf16x8*)(&Bs[wc + ni * 16 + lrow][lk]);
#pragma unroll
    for (int mi = 0; mi < 4; ++mi)
#pragma unroll
      for (int ni = 0; ni < 4; ++ni)
        acc[mi][ni] = __builtin_amdgcn_mfma_f32_16x16x32_bf16(af[mi], bfr[ni], acc[mi][ni], 0, 0, 0);
    __syncthreads();
  }

  float* Cf = (float*)Cv;
  __hip_bfloat16* Cb = (__hip_bfloat16*)Cv;
#pragma unroll
  for (int mi = 0; mi < 4; ++mi)
#pragma unroll
    for (int ni = 0; ni < 4; ++ni)
#pragma unroll
      for (int r = 0; r < 4; ++r) {
        int row = bm + wr + mi * 16 + ((lane >> 4) * 4 + r);
        int col = bn + wc + ni * 16 + (lane & 15);
        size_t idx = (size_t)row * N + col;
        if (EPI == 0) Cf[idx] = acc[mi][ni][r];
        else if (EPI == 1) Cf[idx] += acc[mi][ni][r];
        else Cb[idx] = __float2bfloat16(acc[mi][ni][r]);
      }
}

// ---------------- fallback GEMM: B from f32 weights ----------------
template<int EPI>
__global__ __launch_bounds__(256) void k_gemm(
    const __hip_bfloat16* __restrict__ A, const float* __restrict__ Bw,
    void* __restrict__ Cv, int M, int N, int K) {
  __shared__ __hip_bfloat16 As[128][32];
  __shared__ __hip_bfloat16 Bs[128][40];
  int tid  = threadIdx.x;
  int bm = blockIdx.y * 128, bn = blockIdx.x * 128;
  int wave = tid >> 6, lane = tid & 63;
  int wr = (wave >> 1) * 64, wc = (wave & 1) * 64;
  int lrow = lane & 15, lk = (lane >> 4) * 8;
  f32x4 acc[4][4] = {};
  for (int k0 = 0; k0 < K; k0 += 32) {
#pragma unroll
    for (int i = 0; i < 2; ++i) {
      int L = i * 256 + tid;
      int row = L >> 2, koff = (L & 3) * 8;
      gload_lds16(A + (size_t)(bm + row) * K + k0 + koff, &As[row][koff]);
    }
#pragma unroll
    for (int i = 0; i < 4; ++i) {
      int L = i * 256 + tid;
      int kk = L >> 5;
      int c4 = (L & 31) * 4;
      f32x4 v = *(const f32x4*)(Bw + (size_t)(k0 + kk) * N + bn + c4);
#pragma unroll
      for (int j = 0; j < 4; ++j) Bs[c4 + j][kk] = __float2bfloat16(v[j]);
    }
    __syncthreads();
    bf16x8 af[4], bfr[4];
#pragma unroll
    for (int mi = 0; mi < 4; ++mi)
      af[mi] = *(const bf16x8*)(&As[wr + mi * 16 + lrow][lk]);
#pragma unroll
    for (int ni = 0; ni < 4; ++ni)
      bfr[ni] = *(const bf16x8*)(&Bs[wc + ni * 16 + lrow][lk]);
#pragma unroll
    for (int mi = 0; mi < 4; ++mi)
#pragma unroll
      for (int ni = 0; ni < 4; ++ni)
        acc[mi][ni] = __builtin_amdgcn_mfma_f32_16x16x32_bf16(af[mi], bfr[ni], acc[mi][ni], 0, 0, 0);
    __syncthreads();
  }
  float* Cf = (float*)Cv;
  __hip_bfloat16* Cb = (__hip_bfloat16*)Cv;
#pragma unroll
  for (int mi = 0; mi < 4; ++mi)
#pragma unroll
    for (int ni = 0; ni < 4; ++ni)
#pragma unroll
      for (int r = 0; r < 4; ++r) {
        int row = bm + wr + mi * 16 + ((lane >> 4) * 4 + r);
        int col = bn + wc + ni * 16 + (lane & 15);
        size_t idx = (size_t)row * N + col;
        if (EPI == 0) Cf[idx] = acc[mi][ni][r];
        else if (EPI == 1) Cf[idx] += acc[mi][ni][r];
        else Cb[idx] = __float2bfloat16(acc[mi][ni][r]);
      }
}

// ---------------- RoPE + QKV split/reorder (Q pre-scaled, V transposed) ----------------
__global__ __launch_bounds__(256) void k_rope(const float* __restrict__ qkv,
    __hip_bfloat16* __restrict__ qr, __hip_bfloat16* __restrict__ kr,
    __hip_bfloat16* __restrict__ vt) {
  int rowid = blockIdx.x;
  int b = rowid >> 10, s = rowid & (S_LEN - 1);
  const float* src = qkv + (size_t)rowid * 3072;
  const float kInvLog = 0.20503692777f;  // ln(500000)/64
  const float scale = 0.08838834764831845f;  // 1/sqrt(128)
  __shared__ float cs[64], sn[64];
  if (threadIdx.x < 64) {
    float inv = expf(-(float)threadIdx.x * kInvLog);
    float a = (float)s * inv;
    sincosf(a, &sn[threadIdx.x], &cs[threadIdx.x]);
  }
  __syncthreads();
  for (int it = threadIdx.x; it < NHQ * 64; it += 256) {
    int h = it >> 6, i = it & 63;
    float re = src[h * HDIM + i], im = src[h * HDIM + 64 + i];
    size_t dst = ((size_t)(b * NHQ + h) * S_LEN + s) * HDIM;
    qr[dst + 2 * i]     = __float2bfloat16((re * cs[i] - im * sn[i]) * scale);
    qr[dst + 2 * i + 1] = __float2bfloat16((re * sn[i] + im * cs[i]) * scale);
  }
  for (int it = threadIdx.x; it < NHKV * 64; it += 256) {
    int h = it >> 6, i = it & 63;
    float re = src[DIM + h * HDIM + i], im = src[DIM + h * HDIM + 64 + i];
    size_t dst = ((size_t)(b * NHKV + h) * S_LEN + s) * HDIM;
    kr[dst + 2 * i]     = __float2bfloat16(re * cs[i] - im * sn[i]);
    kr[dst + 2 * i + 1] = __float2bfloat16(re * sn[i] + im * cs[i]);
  }
  // V transposed: vt[b][hk][hd][s]
  for (int it = threadIdx.x; it < NHKV * HDIM; it += 256) {
    int h = it >> 7, d = it & 127;
    vt[(((size_t)b * NHKV + h) * HDIM + d) * S_LEN + s] =
        __float2bfloat16(src[DIM + NHKV * HDIM + it]);
  }
}

// ---------------- MFMA flash attention ----------------
__global__ __launch_bounds__(256) void k_attn_mfma(
    const __hip_bfloat16* __restrict__ Q,   // [B][HQ][S][HD]
    const __hip_bfloat16* __restrict__ Kc,  // [B][HKV][S][HD]
    const __hip_bfloat16* __restrict__ VT,  // [B][HKV][HD][S]
    __hip_bfloat16* __restrict__ O) {       // [B*S][2048], col = h*128+d
  __shared__ __hip_bfloat16 plds[4][16][40];
  int wave = threadIdx.x >> 6, lane = threadIdx.x & 63;
  int gw = blockIdx.x * 4 + wave;
  int qt = gw & 63;
  int bh = gw >> 6;
  int b = bh >> 4, h = bh & 15;
  int hk = h >> 2;
  int q0 = qt * 16;
  int g = lane >> 4, c = lane & 15;
  const __hip_bfloat16* Qb = Q + ((size_t)bh * S_LEN + q0) * HDIM;
  const __hip_bfloat16* Kb = Kc + (size_t)(b * NHKV + hk) * S_LEN * HDIM;
  const __hip_bfloat16* Vb = VT + (size_t)(b * NHKV + hk) * S_LEN * HDIM;

  bf16x8 qf[4];
#pragma unroll
  for (int cn = 0; cn < 4; ++cn)
    qf[cn] = *(const bf16x8*)(Qb + (size_t)c * HDIM + cn * 32 + g * 8);

  f32x4 po[8] = {};
  float m[4], l[4];
#pragma unroll
  for (int r = 0; r < 4; ++r) { m[r] = -1e30f; l[r] = 0.f; }

  int kvend = q0 + 16;
  for (int kv0 = 0; kv0 < kvend; kv0 += 32) {
    f32x4 s0 = {}, s1 = {};
#pragma unroll
    for (int cn = 0; cn < 4; ++cn) {
      bf16x8 k0f = *(const bf16x8*)(Kb + (size_t)(kv0 + c) * HDIM + cn * 32 + g * 8);
      bf16x8 k1f = *(const bf16x8*)(Kb + (size_t)(kv0 + 16 + c) * HDIM + cn * 32 + g * 8);
      s0 = __builtin_amdgcn_mfma_f32_16x16x32_bf16(qf[cn], k0f, s0, 0, 0, 0);
      s1 = __builtin_amdgcn_mfma_f32_16x16x32_bf16(qf[cn], k1f, s1, 0, 0, 0);
    }
    if (kv0 + 31 > q0) {
#pragma unroll
      for (int r = 0; r < 4; ++r) {
        int qrow = q0 + g * 4 + r;
        if (kv0 + c > qrow)      s0[r] = -1e30f;
        if (kv0 + 16 + c > qrow) s1[r] = -1e30f;
      }
    }
    float rm[4];
#pragma unroll
    for (int r = 0; r < 4; ++r) rm[r] = fmaxf(s0[r], s1[r]);
#pragma unroll
    for (int off = 1; off < 16; off <<= 1)
#pragma unroll
      for (int r = 0; r < 4; ++r) rm[r] = fmaxf(rm[r], __shfl_xor(rm[r], off));
    float p0[4], p1[4], rs[4];
#pragma unroll
    for (int r = 0; r < 4; ++r) {
      float mn = fmaxf(m[r], rm[r]);
      float corr = __expf(m[r] - mn);
      m[r] = mn;
      p0[r] = __expf(s0[r] - mn);
      p1[r] = __expf(s1[r] - mn);
      rs[r] = p0[r] + p1[r];
      l[r] *= corr;
#pragma unroll
      for (int t = 0; t < 8; ++t) po[t][r] *= corr;
    }
#pragma unroll
    for (int off = 1; off < 16; off <<= 1)
#pragma unroll
      for (int r = 0; r < 4; ++r) rs[r] += __shfl_xor(rs[r], off);
#pragma unroll
    for (int r = 0; r < 4; ++r) l[r] += rs[r];
#pragma unroll
    for (int r = 0; r < 4; ++r) {
      plds[wave][g * 4 + r][c]      = __float2bfloat16(p0[r]);
      plds[wave][g * 4 + r][16 + c] = __float2bfloat16(p1[r]);
    }
    bf16x8 pf = *(const bf16x8*)&plds[wave][c][g * 8];
#pragma unroll
    for (int t = 0; t < 8; ++t) {
      bf16x8 vf = *(const bf16x8*)(Vb + (size_t)(t * 16 + c) * S_LEN + kv0 + g * 8);
      po[t] = __builtin_amdgcn_mfma_f32_16x16x32_bf16(pf, vf, po[t], 0, 0, 0);
    }
  }
  float inv[4];
#pragma unroll
  for (int r = 0; r < 4; ++r) inv[r] = 1.f / l[r];
  __hip_bfloat16* ob = O + ((size_t)(b * S_LEN) + q0) * DIM + h * HDIM;
#pragma unroll
  for (int t = 0; t < 8; ++t)
#pragma unroll
    for (int r = 0; r < 4; ++r)
      ob[(size_t)(g * 4 + r) * DIM + t * 16 + c] = __float2bfloat16(po[t][r] * inv[r]);
}

// ---------------- swiglu (vectorized bf16x8) ----------------
__global__ __launch_bounds__(256) void k_swiglu(const __hip_bfloat16* __restrict__ gu,
    __hip_bfloat16* __restrict__ h) {
  size_t i = (size_t)blockIdx.x * 256 + threadIdx.x;   // over NROWS*PDIM/8
  size_t row = i >> 10, c8 = (i & 1023) * 8;
  const __hip_bfloat16* grow = gu + row * (2 * PDIM);
  bf16x8 gv = *(const bf16x8*)(grow + c8);
  bf16x8 uv = *(const bf16x8*)(grow + PDIM + c8);
  const __hip_bfloat16* gp = (const __hip_bfloat16*)&gv;
  const __hip_bfloat16* up = (const __hip_bfloat16*)&uv;
  __hip_bfloat16 ov[8];
#pragma unroll
  for (int j = 0; j < 8; ++j) {
    float g = __bfloat162float(gp[j]);
    float u = __bfloat162float(up[j]);
    float s = g / (1.f + __expf(-g));
    ov[j] = __float2bfloat16(s * u);
  }
  *(bf16x8*)(h + row * PDIM + c8) = *(const bf16x8*)ov;
}

extern "C" void kernel_launch(void* const* d_in, const int* in_sizes, int n_in,
                              void* d_out, int out_size, void* d_ws, size_t ws_size,
                              hipStream_t stream) {
  const int*   tokens    = (const int*)d_in[0];
  const float* emb       = (const float*)d_in[1];
  const float* w_qkv     = (const float*)d_in[2];
  const float* w_o       = (const float*)d_in[3];
  const float* w_gate_up = (const float*)d_in[4];
  const float* w_down    = (const float*)d_in[5];
  const float* ln_attn   = (const float*)d_in[6];
  const float* ln_ffn    = (const float*)d_in[7];
  const float* ln_f      = (const float*)d_in[8];
  const float* w_lm      = (const float*)d_in[9];
  float* out = (float*)d_out;

  char* ws = (char*)d_ws;
  float* x = (float*)ws;                    ws += (size_t)NROWS * DIM * 4;
  __hip_bfloat16* xn = (__hip_bfloat16*)ws; ws += (size_t)NROWS * DIM * 2;
  float* qkv = (float*)ws;                  ws += (size_t)NROWS * 3072 * 4;
  __hip_bfloat16* qr = (__hip_bfloat16*)ws; ws += (size_t)2 * NHQ * S_LEN * HDIM * 2;
  __hip_bfloat16* kr = (__hip_bfloat16*)ws; ws += (size_t)2 * NHKV * S_LEN * HDIM * 2;
  __hip_bfloat16* vt = (__hip_bfloat16*)ws; ws += (size_t)2 * NHKV * S_LEN * HDIM * 2;
  __hip_bfloat16* ao = (__hip_bfloat16*)ws; ws += (size_t)NROWS * DIM * 2;
  __hip_bfloat16* gu = (__hip_bfloat16*)ws; ws += (size_t)NROWS * 2 * PDIM * 2;
  __hip_bfloat16* hb = (__hip_bfloat16*)ws; ws += (size_t)NROWS * PDIM * 2;
  __hip_bfloat16* wbuf = (__hip_bfloat16*)ws;           // JIT bf16 W^T buffer
  size_t need = (size_t)(ws - (char*)d_ws) + (size_t)VOCAB * DIM * 2;
  bool bf16w = ws_size >= need;

  k_embed<<<NROWS, 256, 0, stream>>>(tokens, emb, x);

  for (int l = 0; l < NLAYER; ++l) {
    k_rmsnorm<<<NROWS, 256, 0, stream>>>(x, ln_attn + (size_t)l * DIM, xn);
    if (bf16w) {
      k_wt<<<dim3(3072 / 64, DIM / 64), 256, 0, stream>>>(
          w_qkv + (size_t)l * DIM * 3072, wbuf, DIM, 3072);
      k_gemm_bt<0><<<(NROWS / 128) * (3072 / 128), 256, 0, stream>>>(
          xn, wbuf, qkv, NROWS, 3072, DIM);
    } else {
      k_gemm<0><<<dim3(3072 / 128, NROWS / 128), 256, 0, stream>>>(
          xn, w_qkv + (size_t)l * DIM * 3072, qkv, NROWS, 3072, DIM);
    }
    k_rope<<<NROWS, 256, 0, stream>>>(qkv, qr, kr, vt);
    k_attn_mfma<<<(2 * NHQ * (S_LEN / 16)) / 4, 256, 0, stream>>>(qr, kr, vt, ao);
    if (bf16w) {
      k_wt<<<dim3(DIM / 64, DIM / 64), 256, 0, stream>>>(
          w_o + (size_t)l * DIM * DIM, wbuf, DIM, DIM);
      k_gemm_bt<1><<<(NROWS / 128) * (DIM / 128), 256, 0, stream>>>(
          ao, wbuf, x, NROWS, DIM, DIM);
    } else {
      k_gemm<1><<<dim3(DIM / 128, NROWS / 128), 256, 0, stream>>>(
          ao, w_o + (size_t)l * DIM * DIM, x, NROWS, DIM, DIM);
    }
    k_rmsnorm<<<NROWS, 256, 0, stream>>>(x, ln_ffn + (size_t)l * DIM, xn);
    if (bf16w) {
      k_wt<<<dim3(2 * PDIM / 64, DIM / 64), 256, 0, stream>>>(
          w_gate_up + (size_t)l * DIM * 2 * PDIM, wbuf, DIM, 2 * PDIM);
      k_gemm256<2><<<8 * (2 * PDIM / 256), 512, 0, stream>>>(
          xn, wbuf, gu, NROWS, 2 * PDIM, DIM);
    } else {
      k_gemm<2><<<dim3(2 * PDIM / 128, NROWS / 128), 256, 0, stream>>>(
          xn, w_gate_up + (size_t)l * DIM * 2 * PDIM, gu, NROWS, 2 * PDIM, DIM);
    }
    k_swiglu<<<(NROWS * PDIM / 8) / 256, 256, 0, stream>>>(gu, hb);
    if (bf16w) {
      k_wt<<<dim3(DIM / 64, PDIM / 64), 256, 0, stream>>>(
          w_down + (size_t)l * PDIM * DIM, wbuf, PDIM, DIM);
      k_gemm_bt<1><<<(NROWS / 128) * (DIM / 128), 256, 0, stream>>>(
          hb, wbuf, x, NROWS, DIM, PDIM);
    } else {
      k_gemm<1><<<dim3(DIM / 128, NROWS / 128), 256, 0, stream>>>(
          hb, w_down + (size_t)l * PDIM * DIM, x, NROWS, DIM, PDIM);
    }
  }

  k_rmsnorm<<<NROWS, 256, 0, stream>>>(x, ln_f, xn);
  if (bf16w) {
    k_wt<<<dim3(VOCAB / 64, DIM / 64), 256, 0, stream>>>(w_lm, wbuf, DIM, VOCAB);
    k_gemm256<0><<<8 * (VOCAB / 256), 512, 0, stream>>>(
        xn, wbuf, out, NROWS, VOCAB, DIM);
  } else {
    k_gemm<0><<<dim3(VOCAB / 128, NROWS / 128), 256, 0, stream>>>(
        xn, w_lm, out, NROWS, VOCAB, DIM);
  }
}

// Round 5
// 2739.122 us; speedup vs baseline: 4.6177x; 1.1166x over previous
//
#include <hip/hip_runtime.h>
#include <hip/hip_bf16.h>
#include <math.h>

#define S_LEN 1024
#define DIM   2048
#define NHQ   16
#define NHKV  4
#define HDIM  128
#define PDIM  8192
#define VOCAB 32000
#define NLAYER 4
#define NROWS (2 * S_LEN)   // B*S = 2048

typedef __attribute__((ext_vector_type(4))) float f32x4;
typedef __attribute__((ext_vector_type(8))) short bf16x8;

__device__ __forceinline__ void gload_lds16(const void* g, void* l) {
  __builtin_amdgcn_global_load_lds(
      (const __attribute__((address_space(1))) unsigned int*)g,
      (__attribute__((address_space(3))) unsigned int*)l, 16, 0, 0);
}

#define FENCE() asm volatile("" ::: "memory")

// ---------------- embedding gather (f32) ----------------
__global__ __launch_bounds__(256) void k_embed(const int* __restrict__ tokens,
    const float* __restrict__ emb, float* __restrict__ x) {
  int row = blockIdx.x;
  int tok = tokens[row];
  const f32x4* src = (const f32x4*)(emb + (size_t)tok * DIM);
  f32x4* dst = (f32x4*)(x + (size_t)row * DIM);
  for (int i = threadIdx.x; i < DIM / 4; i += 256) dst[i] = src[i];
}

// ---------------- rmsnorm f32 -> bf16 ----------------
__global__ __launch_bounds__(256) void k_rmsnorm(const float* __restrict__ x,
    const float* __restrict__ w, __hip_bfloat16* __restrict__ out) {
  int row = blockIdx.x;
  const float* xr = x + (size_t)row * DIM;
  float ss = 0.f;
  for (int i = threadIdx.x; i < DIM; i += 256) { float v = xr[i]; ss += v * v; }
  for (int off = 32; off; off >>= 1) ss += __shfl_xor(ss, off);
  __shared__ float wsum[4];
  if ((threadIdx.x & 63) == 0) wsum[threadIdx.x >> 6] = ss;
  __syncthreads();
  float tot = wsum[0] + wsum[1] + wsum[2] + wsum[3];
  float r = rsqrtf(tot / (float)DIM + 1e-5f);
  __hip_bfloat16* orow = out + (size_t)row * DIM;
  for (int i = threadIdx.x; i < DIM; i += 256)
    orow[i] = __float2bfloat16(w[i] * (xr[i] * r));
}

// ---------------- weight transpose+convert: W[K][N] f32 -> WT[N][K] bf16 ----------------
__global__ __launch_bounds__(256) void k_wt(const float* __restrict__ W,
    __hip_bfloat16* __restrict__ WT, int K, int N) {
  __shared__ __hip_bfloat16 t[64][72];   // [n][k], +8 pad
  int k0 = blockIdx.y * 64, n0 = blockIdx.x * 64;
  int r = threadIdx.x >> 4;          // 0..15
  int c4 = (threadIdx.x & 15) * 4;   // 0..60
#pragma unroll
  for (int i = 0; i < 4; ++i) {
    int k = r + i * 16;
    f32x4 v = *(const f32x4*)(W + (size_t)(k0 + k) * N + n0 + c4);
#pragma unroll
    for (int j = 0; j < 4; ++j) t[c4 + j][k] = __float2bfloat16(v[j]);
  }
  __syncthreads();
  int n = threadIdx.x >> 2, kc = (threadIdx.x & 3) * 16;
  bf16x8* dst = (bf16x8*)(WT + (size_t)(n0 + n) * K + k0 + kc);
  dst[0] = *(const bf16x8*)&t[n][kc];
  dst[1] = *(const bf16x8*)&t[n][kc + 8];
}

// ---------------- big GEMM: 256x256, BK=64, 8 waves, counted-vmcnt 2-deep pipeline ----------------
// A bf16 [M][K], BT bf16 [N][K]. Requires M==2048 (8 m-tiles) and N%256==0.
// EPI: 0 = store f32, 1 = add into f32, 2 = store bf16
template<int EPI>
__global__ __launch_bounds__(512) void k_gemm256(
    const __hip_bfloat16* __restrict__ A, const __hip_bfloat16* __restrict__ BT,
    void* __restrict__ Cv, int M, int N, int K) {
  __shared__ __hip_bfloat16 As[2][256][64];   // 64 KiB
  __shared__ __hip_bfloat16 Bs[2][256][64];   // 64 KiB
  int tid = threadIdx.x;
  int bid = blockIdx.x;
  int mt = bid & 7, nt = bid >> 3;   // XCD x owns m-strip x, sweeps n
  int bm = mt << 8, bn = nt << 8;
  int wave = tid >> 6, lane = tid & 63;
  int wm = wave >> 2, wn = wave & 3;           // 2x4 wave grid
  int g = lane >> 4, c = lane & 15;
  f32x4 acc[8][4] = {};

  // stage one 256x64 K-tile of A and B (8 vmem insts/wave).
  // Physical chunk (row,pc) holds logical chunk pc ^ (row&7) (inverse-swizzled
  // source, linear lane-contiguous LDS dest).
  auto stage = [&](int buf, int k0) {
#pragma unroll
    for (int i = 0; i < 4; ++i) {
      int ci = i * 512 + tid;          // 0..2047, lane-contiguous dest
      int row = ci >> 3, pc = ci & 7;
      int jl = pc ^ (row & 7);
      gload_lds16(A + (size_t)(bm + row) * K + k0 + jl * 8, &As[buf][row][pc * 8]);
      gload_lds16(BT + (size_t)(bn + row) * K + k0 + jl * 8, &Bs[buf][row][pc * 8]);
    }
  };

  int ntiles = K >> 6;
  stage(0, 0);
  if (ntiles > 1) stage(1, 64);

  for (int t = 0; t < ntiles; ++t) {
    int cur = t & 1;
    // wait for tile t's 8 loads only; tile t+1's stay in flight across barrier
    if (t + 1 < ntiles) asm volatile("s_waitcnt vmcnt(8)" ::: "memory");
    else                asm volatile("s_waitcnt vmcnt(0)" ::: "memory");
    __builtin_amdgcn_s_barrier();
    FENCE();
    __builtin_amdgcn_sched_barrier(0);
#pragma unroll
    for (int kk = 0; kk < 2; ++kk) {
      bf16x8 af[8], bv[4];
#pragma unroll
      for (int mi = 0; mi < 8; ++mi) {
        int row = wm * 128 + mi * 16 + c;
        int ch = (kk * 4 + g) ^ (row & 7);
        af[mi] = *(const bf16x8*)&As[cur][row][ch * 8];
      }
#pragma unroll
      for (int ni = 0; ni < 4; ++ni) {
        int row = wn * 64 + ni * 16 + c;
        int ch = (kk * 4 + g) ^ (row & 7);
        bv[ni] = *(const bf16x8*)&Bs[cur][row][ch * 8];
      }
      __builtin_amdgcn_s_setprio(1);
#pragma unroll
      for (int mi = 0; mi < 8; ++mi)
#pragma unroll
        for (int ni = 0; ni < 4; ++ni)
          acc[mi][ni] = __builtin_amdgcn_mfma_f32_16x16x32_bf16(af[mi], bv[ni], acc[mi][ni], 0, 0, 0);
      __builtin_amdgcn_s_setprio(0);
    }
    FENCE();
    __builtin_amdgcn_s_barrier();    // all waves done reading buf cur
    FENCE();
    if (t + 2 < ntiles) stage(cur, (t + 2) << 6);
  }

  float* Cf = (float*)Cv;
  __hip_bfloat16* Cb = (__hip_bfloat16*)Cv;
  int row0 = bm + wm * 128, col0 = bn + wn * 64;
#pragma unroll
  for (int mi = 0; mi < 8; ++mi)
#pragma unroll
    for (int ni = 0; ni < 4; ++ni)
#pragma unroll
      for (int r = 0; r < 4; ++r) {
        int row = row0 + mi * 16 + g * 4 + r;
        int col = col0 + ni * 16 + c;
        size_t idx = (size_t)row * N + col;
        if (EPI == 0) Cf[idx] = acc[mi][ni][r];
        else if (EPI == 1) Cf[idx] += acc[mi][ni][r];
        else Cb[idx] = __float2bfloat16(acc[mi][ni][r]);
      }
}

// ---------------- 128x128 GEMM, BK=64, counted-vmcnt 2-deep, swizzled LDS ----------------
template<int EPI>
__global__ __launch_bounds__(256) void k_gemm_bt(
    const __hip_bfloat16* __restrict__ A, const __hip_bfloat16* __restrict__ BT,
    void* __restrict__ Cv, int M, int N, int K) {
  __shared__ __hip_bfloat16 As[2][128][64];   // 32 KiB
  __shared__ __hip_bfloat16 Bs[2][128][64];   // 32 KiB
  int nm = M >> 7;
  int bid = blockIdx.x;
  int mt, nt;
  if (nm == 16) {
    int xcd = bid & 7;
    int seq = bid >> 3;
    mt = (xcd << 1) | (seq & 1);
    nt = seq >> 1;
  } else {
    mt = bid % nm;
    nt = bid / nm;
  }
  int bm = mt << 7, bn = nt << 7;
  int tid  = threadIdx.x;
  int wave = tid >> 6, lane = tid & 63;
  int wr = (wave >> 1) * 64, wc = (wave & 1) * 64;
  int g = lane >> 4, c = lane & 15;
  f32x4 acc[4][4] = {};

  auto stage = [&](int buf, int k0) {   // 8 vmem insts/wave
#pragma unroll
    for (int i = 0; i < 4; ++i) {
      int ci = i * 256 + tid;            // 0..1023
      int row = ci >> 3, pc = ci & 7;
      int jl = pc ^ (row & 7);
      gload_lds16(A + (size_t)(bm + row) * K + k0 + jl * 8, &As[buf][row][pc * 8]);
      gload_lds16(BT + (size_t)(bn + row) * K + k0 + jl * 8, &Bs[buf][row][pc * 8]);
    }
  };

  int ntiles = K >> 6;
  stage(0, 0);
  if (ntiles > 1) stage(1, 64);

  for (int t = 0; t < ntiles; ++t) {
    int cur = t & 1;
    if (t + 1 < ntiles) asm volatile("s_waitcnt vmcnt(8)" ::: "memory");
    else                asm volatile("s_waitcnt vmcnt(0)" ::: "memory");
    __builtin_amdgcn_s_barrier();
    FENCE();
    __builtin_amdgcn_sched_barrier(0);
#pragma unroll
    for (int kk = 0; kk < 2; ++kk) {
      bf16x8 af[4], bv[4];
#pragma unroll
      for (int mi = 0; mi < 4; ++mi) {
        int row = wr + mi * 16 + c;
        int ch = (kk * 4 + g) ^ (row & 7);
        af[mi] = *(const bf16x8*)&As[cur][row][ch * 8];
      }
#pragma unroll
      for (int ni = 0; ni < 4; ++ni) {
        int row = wc + ni * 16 + c;
        int ch = (kk * 4 + g) ^ (row & 7);
        bv[ni] = *(const bf16x8*)&Bs[cur][row][ch * 8];
      }
      __builtin_amdgcn_s_setprio(1);
#pragma unroll
      for (int mi = 0; mi < 4; ++mi)
#pragma unroll
        for (int ni = 0; ni < 4; ++ni)
          acc[mi][ni] = __builtin_amdgcn_mfma_f32_16x16x32_bf16(af[mi], bv[ni], acc[mi][ni], 0, 0, 0);
      __builtin_amdgcn_s_setprio(0);
    }
    FENCE();
    __builtin_amdgcn_s_barrier();
    FENCE();
    if (t + 2 < ntiles) stage(cur, (t + 2) << 6);
  }

  float* Cf = (float*)Cv;
  __hip_bfloat16* Cb = (__hip_bfloat16*)Cv;
#pragma unroll
  for (int mi = 0; mi < 4; ++mi)
#pragma unroll
    for (int ni = 0; ni < 4; ++ni)
#pragma unroll
      for (int r = 0; r < 4; ++r) {
        int row = bm + wr + mi * 16 + g * 4 + r;
        int col = bn + wc + ni * 16 + c;
        size_t idx = (size_t)row * N + col;
        if (EPI == 0) Cf[idx] = acc[mi][ni][r];
        else if (EPI == 1) Cf[idx] += acc[mi][ni][r];
        else Cb[idx] = __float2bfloat16(acc[mi][ni][r]);
      }
}

// ---------------- fallback GEMM: B from f32 weights ----------------
template<int EPI>
__global__ __launch_bounds__(256) void k_gemm(
    const __hip_bfloat16* __restrict__ A, const float* __restrict__ Bw,
    void* __restrict__ Cv, int M, int N, int K) {
  __shared__ __hip_bfloat16 As[128][32];
  __shared__ __hip_bfloat16 Bs[128][40];
  int tid  = threadIdx.x;
  int bm = blockIdx.y * 128, bn = blockIdx.x * 128;
  int wave = tid >> 6, lane = tid & 63;
  int wr = (wave >> 1) * 64, wc = (wave & 1) * 64;
  int lrow = lane & 15, lk = (lane >> 4) * 8;
  f32x4 acc[4][4] = {};
  for (int k0 = 0; k0 < K; k0 += 32) {
#pragma unroll
    for (int i = 0; i < 2; ++i) {
      int L = i * 256 + tid;
      int row = L >> 2, koff = (L & 3) * 8;
      gload_lds16(A + (size_t)(bm + row) * K + k0 + koff, &As[row][koff]);
    }
#pragma unroll
    for (int i = 0; i < 4; ++i) {
      int L = i * 256 + tid;
      int kk = L >> 5;
      int c4 = (L & 31) * 4;
      f32x4 v = *(const f32x4*)(Bw + (size_t)(k0 + kk) * N + bn + c4);
#pragma unroll
      for (int j = 0; j < 4; ++j) Bs[c4 + j][kk] = __float2bfloat16(v[j]);
    }
    __syncthreads();
    bf16x8 af[4], bfr[4];
#pragma unroll
    for (int mi = 0; mi < 4; ++mi)
      af[mi] = *(const bf16x8*)(&As[wr + mi * 16 + lrow][lk]);
#pragma unroll
    for (int ni = 0; ni < 4; ++ni)
      bfr[ni] = *(const bf16x8*)(&Bs[wc + ni * 16 + lrow][lk]);
#pragma unroll
    for (int mi = 0; mi < 4; ++mi)
#pragma unroll
      for (int ni = 0; ni < 4; ++ni)
        acc[mi][ni] = __builtin_amdgcn_mfma_f32_16x16x32_bf16(af[mi], bfr[ni], acc[mi][ni], 0, 0, 0);
    __syncthreads();
  }
  float* Cf = (float*)Cv;
  __hip_bfloat16* Cb = (__hip_bfloat16*)Cv;
#pragma unroll
  for (int mi = 0; mi < 4; ++mi)
#pragma unroll
    for (int ni = 0; ni < 4; ++ni)
#pragma unroll
      for (int r = 0; r < 4; ++r) {
        int row = bm + wr + mi * 16 + ((lane >> 4) * 4 + r);
        int col = bn + wc + ni * 16 + (lane & 15);
        size_t idx = (size_t)row * N + col;
        if (EPI == 0) Cf[idx] = acc[mi][ni][r];
        else if (EPI == 1) Cf[idx] += acc[mi][ni][r];
        else Cb[idx] = __float2bfloat16(acc[mi][ni][r]);
      }
}

// ---------------- RoPE + QKV split/reorder (Q pre-scaled, V transposed) ----------------
__global__ __launch_bounds__(256) void k_rope(const float* __restrict__ qkv,
    __hip_bfloat16* __restrict__ qr, __hip_bfloat16* __restrict__ kr,
    __hip_bfloat16* __restrict__ vt) {
  int rowid = blockIdx.x;
  int b = rowid >> 10, s = rowid & (S_LEN - 1);
  const float* src = qkv + (size_t)rowid * 3072;
  const float kInvLog = 0.20503692777f;  // ln(500000)/64
  const float scale = 0.08838834764831845f;  // 1/sqrt(128)
  __shared__ float cs[64], sn[64];
  if (threadIdx.x < 64) {
    float inv = expf(-(float)threadIdx.x * kInvLog);
    float a = (float)s * inv;
    sincosf(a, &sn[threadIdx.x], &cs[threadIdx.x]);
  }
  __syncthreads();
  for (int it = threadIdx.x; it < NHQ * 64; it += 256) {
    int h = it >> 6, i = it & 63;
    float re = src[h * HDIM + i], im = src[h * HDIM + 64 + i];
    size_t dst = ((size_t)(b * NHQ + h) * S_LEN + s) * HDIM;
    qr[dst + 2 * i]     = __float2bfloat16((re * cs[i] - im * sn[i]) * scale);
    qr[dst + 2 * i + 1] = __float2bfloat16((re * sn[i] + im * cs[i]) * scale);
  }
  for (int it = threadIdx.x; it < NHKV * 64; it += 256) {
    int h = it >> 6, i = it & 63;
    float re = src[DIM + h * HDIM + i], im = src[DIM + h * HDIM + 64 + i];
    size_t dst = ((size_t)(b * NHKV + h) * S_LEN + s) * HDIM;
    kr[dst + 2 * i]     = __float2bfloat16(re * cs[i] - im * sn[i]);
    kr[dst + 2 * i + 1] = __float2bfloat16(re * sn[i] + im * cs[i]);
  }
  // V transposed: vt[b][hk][hd][s]
  for (int it = threadIdx.x; it < NHKV * HDIM; it += 256) {
    int h = it >> 7, d = it & 127;
    vt[(((size_t)b * NHKV + h) * HDIM + d) * S_LEN + s] =
        __float2bfloat16(src[DIM + NHKV * HDIM + it]);
  }
}

// ---------------- MFMA flash attention ----------------
__global__ __launch_bounds__(256) void k_attn_mfma(
    const __hip_bfloat16* __restrict__ Q,   // [B][HQ][S][HD]
    const __hip_bfloat16* __restrict__ Kc,  // [B][HKV][S][HD]
    const __hip_bfloat16* __restrict__ VT,  // [B][HKV][HD][S]
    __hip_bfloat16* __restrict__ O) {       // [B*S][2048], col = h*128+d
  __shared__ __hip_bfloat16 plds[4][16][40];
  int wave = threadIdx.x >> 6, lane = threadIdx.x & 63;
  int gw = blockIdx.x * 4 + wave;
  int qt = gw & 63;
  int bh = gw >> 6;
  int b = bh >> 4, h = bh & 15;
  int hk = h >> 2;
  int q0 = qt * 16;
  int g = lane >> 4, c = lane & 15;
  const __hip_bfloat16* Qb = Q + ((size_t)bh * S_LEN + q0) * HDIM;
  const __hip_bfloat16* Kb = Kc + (size_t)(b * NHKV + hk) * S_LEN * HDIM;
  const __hip_bfloat16* Vb = VT + (size_t)(b * NHKV + hk) * S_LEN * HDIM;

  bf16x8 qf[4];
#pragma unroll
  for (int cn = 0; cn < 4; ++cn)
    qf[cn] = *(const bf16x8*)(Qb + (size_t)c * HDIM + cn * 32 + g * 8);

  f32x4 po[8] = {};
  float m[4], l[4];
#pragma unroll
  for (int r = 0; r < 4; ++r) { m[r] = -1e30f; l[r] = 0.f; }

  int kvend = q0 + 16;
  for (int kv0 = 0; kv0 < kvend; kv0 += 32) {
    f32x4 s0 = {}, s1 = {};
#pragma unroll
    for (int cn = 0; cn < 4; ++cn) {
      bf16x8 k0f = *(const bf16x8*)(Kb + (size_t)(kv0 + c) * HDIM + cn * 32 + g * 8);
      bf16x8 k1f = *(const bf16x8*)(Kb + (size_t)(kv0 + 16 + c) * HDIM + cn * 32 + g * 8);
      s0 = __builtin_amdgcn_mfma_f32_16x16x32_bf16(qf[cn], k0f, s0, 0, 0, 0);
      s1 = __builtin_amdgcn_mfma_f32_16x16x32_bf16(qf[cn], k1f, s1, 0, 0, 0);
    }
    if (kv0 + 31 > q0) {
#pragma unroll
      for (int r = 0; r < 4; ++r) {
        int qrow = q0 + g * 4 + r;
        if (kv0 + c > qrow)      s0[r] = -1e30f;
        if (kv0 + 16 + c > qrow) s1[r] = -1e30f;
      }
    }
    float rm[4];
#pragma unroll
    for (int r = 0; r < 4; ++r) rm[r] = fmaxf(s0[r], s1[r]);
#pragma unroll
    for (int off = 1; off < 16; off <<= 1)
#pragma unroll
      for (int r = 0; r < 4; ++r) rm[r] = fmaxf(rm[r], __shfl_xor(rm[r], off));
    float p0[4], p1[4], rs[4];
#pragma unroll
    for (int r = 0; r < 4; ++r) {
      float mn = fmaxf(m[r], rm[r]);
      float corr = __expf(m[r] - mn);
      m[r] = mn;
      p0[r] = __expf(s0[r] - mn);
      p1[r] = __expf(s1[r] - mn);
      rs[r] = p0[r] + p1[r];
      l[r] *= corr;
#pragma unroll
      for (int t = 0; t < 8; ++t) po[t][r] *= corr;
    }
#pragma unroll
    for (int off = 1; off < 16; off <<= 1)
#pragma unroll
      for (int r = 0; r < 4; ++r) rs[r] += __shfl_xor(rs[r], off);
#pragma unroll
    for (int r = 0; r < 4; ++r) l[r] += rs[r];
#pragma unroll
    for (int r = 0; r < 4; ++r) {
      plds[wave][g * 4 + r][c]      = __float2bfloat16(p0[r]);
      plds[wave][g * 4 + r][16 + c] = __float2bfloat16(p1[r]);
    }
    bf16x8 pf = *(const bf16x8*)&plds[wave][c][g * 8];
#pragma unroll
    for (int t = 0; t < 8; ++t) {
      bf16x8 vf = *(const bf16x8*)(Vb + (size_t)(t * 16 + c) * S_LEN + kv0 + g * 8);
      po[t] = __builtin_amdgcn_mfma_f32_16x16x32_bf16(pf, vf, po[t], 0, 0, 0);
    }
  }
  float inv[4];
#pragma unroll
  for (int r = 0; r < 4; ++r) inv[r] = 1.f / l[r];
  __hip_bfloat16* ob = O + ((size_t)(b * S_LEN) + q0) * DIM + h * HDIM;
#pragma unroll
  for (int t = 0; t < 8; ++t)
#pragma unroll
    for (int r = 0; r < 4; ++r)
      ob[(size_t)(g * 4 + r) * DIM + t * 16 + c] = __float2bfloat16(po[t][r] * inv[r]);
}

// ---------------- swiglu (vectorized bf16x8) ----------------
__global__ __launch_bounds__(256) void k_swiglu(const __hip_bfloat16* __restrict__ gu,
    __hip_bfloat16* __restrict__ h) {
  size_t i = (size_t)blockIdx.x * 256 + threadIdx.x;   // over NROWS*PDIM/8
  size_t row = i >> 10, c8 = (i & 1023) * 8;
  const __hip_bfloat16* grow = gu + row * (2 * PDIM);
  bf16x8 gv = *(const bf16x8*)(grow + c8);
  bf16x8 uv = *(const bf16x8*)(grow + PDIM + c8);
  const __hip_bfloat16* gp = (const __hip_bfloat16*)&gv;
  const __hip_bfloat16* up = (const __hip_bfloat16*)&uv;
  __hip_bfloat16 ov[8];
#pragma unroll
  for (int j = 0; j < 8; ++j) {
    float g = __bfloat162float(gp[j]);
    float u = __bfloat162float(up[j]);
    float s = g / (1.f + __expf(-g));
    ov[j] = __float2bfloat16(s * u);
  }
  *(bf16x8*)(h + row * PDIM + c8) = *(const bf16x8*)ov;
}

extern "C" void kernel_launch(void* const* d_in, const int* in_sizes, int n_in,
                              void* d_out, int out_size, void* d_ws, size_t ws_size,
                              hipStream_t stream) {
  const int*   tokens    = (const int*)d_in[0];
  const float* emb       = (const float*)d_in[1];
  const float* w_qkv     = (const float*)d_in[2];
  const float* w_o       = (const float*)d_in[3];
  const float* w_gate_up = (const float*)d_in[4];
  const float* w_down    = (const float*)d_in[5];
  const float* ln_attn   = (const float*)d_in[6];
  const float* ln_ffn    = (const float*)d_in[7];
  const float* ln_f      = (const float*)d_in[8];
  const float* w_lm      = (const float*)d_in[9];
  float* out = (float*)d_out;

  char* ws = (char*)d_ws;
  float* x = (float*)ws;                    ws += (size_t)NROWS * DIM * 4;
  __hip_bfloat16* xn = (__hip_bfloat16*)ws; ws += (size_t)NROWS * DIM * 2;
  float* qkv = (float*)ws;                  ws += (size_t)NROWS * 3072 * 4;
  __hip_bfloat16* qr = (__hip_bfloat16*)ws; ws += (size_t)2 * NHQ * S_LEN * HDIM * 2;
  __hip_bfloat16* kr = (__hip_bfloat16*)ws; ws += (size_t)2 * NHKV * S_LEN * HDIM * 2;
  __hip_bfloat16* vt = (__hip_bfloat16*)ws; ws += (size_t)2 * NHKV * S_LEN * HDIM * 2;
  __hip_bfloat16* ao = (__hip_bfloat16*)ws; ws += (size_t)NROWS * DIM * 2;
  __hip_bfloat16* gu = (__hip_bfloat16*)ws; ws += (size_t)NROWS * 2 * PDIM * 2;
  __hip_bfloat16* hb = (__hip_bfloat16*)ws; ws += (size_t)NROWS * PDIM * 2;
  __hip_bfloat16* wbuf = (__hip_bfloat16*)ws;           // JIT bf16 W^T buffer
  size_t need = (size_t)(ws - (char*)d_ws) + (size_t)VOCAB * DIM * 2;
  bool bf16w = ws_size >= need;

  k_embed<<<NROWS, 256, 0, stream>>>(tokens, emb, x);

  for (int l = 0; l < NLAYER; ++l) {
    k_rmsnorm<<<NROWS, 256, 0, stream>>>(x, ln_attn + (size_t)l * DIM, xn);
    if (bf16w) {
      k_wt<<<dim3(3072 / 64, DIM / 64), 256, 0, stream>>>(
          w_qkv + (size_t)l * DIM * 3072, wbuf, DIM, 3072);
      k_gemm_bt<0><<<(NROWS / 128) * (3072 / 128), 256, 0, stream>>>(
          xn, wbuf, qkv, NROWS, 3072, DIM);
    } else {
      k_gemm<0><<<dim3(3072 / 128, NROWS / 128), 256, 0, stream>>>(
          xn, w_qkv + (size_t)l * DIM * 3072, qkv, NROWS, 3072, DIM);
    }
    k_rope<<<NROWS, 256, 0, stream>>>(qkv, qr, kr, vt);
    k_attn_mfma<<<(2 * NHQ * (S_LEN / 16)) / 4, 256, 0, stream>>>(qr, kr, vt, ao);
    if (bf16w) {
      k_wt<<<dim3(DIM / 64, DIM / 64), 256, 0, stream>>>(
          w_o + (size_t)l * DIM * DIM, wbuf, DIM, DIM);
      k_gemm_bt<1><<<(NROWS / 128) * (DIM / 128), 256, 0, stream>>>(
          ao, wbuf, x, NROWS, DIM, DIM);
    } else {
      k_gemm<1><<<dim3(DIM / 128, NROWS / 128), 256, 0, stream>>>(
          ao, w_o + (size_t)l * DIM * DIM, x, NROWS, DIM, DIM);
    }
    k_rmsnorm<<<NROWS, 256, 0, stream>>>(x, ln_ffn + (size_t)l * DIM, xn);
    if (bf16w) {
      k_wt<<<dim3(2 * PDIM / 64, DIM / 64), 256, 0, stream>>>(
          w_gate_up + (size_t)l * DIM * 2 * PDIM, wbuf, DIM, 2 * PDIM);
      k_gemm256<2><<<8 * (2 * PDIM / 256), 512, 0, stream>>>(
          xn, wbuf, gu, NROWS, 2 * PDIM, DIM);
    } else {
      k_gemm<2><<<dim3(2 * PDIM / 128, NROWS / 128), 256, 0, stream>>>(
          xn, w_gate_up + (size_t)l * DIM * 2 * PDIM, gu, NROWS, 2 * PDIM, DIM);
    }
    k_swiglu<<<(NROWS * PDIM / 8) / 256, 256, 0, stream>>>(gu, hb);
    if (bf16w) {
      k_wt<<<dim3(DIM / 64, PDIM / 64), 256, 0, stream>>>(
          w_down + (size_t)l * PDIM * DIM, wbuf, PDIM, DIM);
      k_gemm_bt<1><<<(NROWS / 128) * (DIM / 128), 256, 0, stream>>>(
          hb, wbuf, x, NROWS, DIM, PDIM);
    } else {
      k_gemm<1><<<dim3(DIM / 128, NROWS / 128), 256, 0, stream>>>(
          hb, w_down + (size_t)l * PDIM * DIM, x, NROWS, DIM, PDIM);
    }
  }

  k_rmsnorm<<<NROWS, 256, 0, stream>>>(x, ln_f, xn);
  if (bf16w) {
    k_wt<<<dim3(VOCAB / 64, DIM / 64), 256, 0, stream>>>(w_lm, wbuf, DIM, VOCAB);
    k_gemm256<0><<<8 * (VOCAB / 256), 512, 0, stream>>>(
        xn, wbuf, out, NROWS, VOCAB, DIM);
  } else {
    k_gemm<0><<<dim3(VOCAB / 128, NROWS / 128), 256, 0, stream>>>(
        xn, w_lm, out, NROWS, VOCAB, DIM);
  }
}

// Round 6
// 2696.710 us; speedup vs baseline: 4.6903x; 1.0157x over previous
//
#include <hip/hip_runtime.h>
#include <hip/hip_bf16.h>
#include <math.h>

#define S_LEN 1024
#define DIM   2048
#define NHQ   16
#define NHKV  4
#define HDIM  128
#define PDIM  8192
#define VOCAB 32000
#define NLAYER 4
#define NROWS (2 * S_LEN)   // B*S = 2048

typedef __attribute__((ext_vector_type(4))) float f32x4;
typedef __attribute__((ext_vector_type(8))) short bf16x8;

__device__ __forceinline__ void gload_lds16(const void* g, void* l) {
  __builtin_amdgcn_global_load_lds(
      (const __attribute__((address_space(1))) unsigned int*)g,
      (__attribute__((address_space(3))) unsigned int*)l, 16, 0, 0);
}

#define FENCE() asm volatile("" ::: "memory")

// ---------------- embedding gather (f32) ----------------
__global__ __launch_bounds__(256) void k_embed(const int* __restrict__ tokens,
    const float* __restrict__ emb, float* __restrict__ x) {
  int row = blockIdx.x;
  int tok = tokens[row];
  const f32x4* src = (const f32x4*)(emb + (size_t)tok * DIM);
  f32x4* dst = (f32x4*)(x + (size_t)row * DIM);
  for (int i = threadIdx.x; i < DIM / 4; i += 256) dst[i] = src[i];
}

// ---------------- rmsnorm f32 -> bf16 ----------------
__global__ __launch_bounds__(256) void k_rmsnorm(const float* __restrict__ x,
    const float* __restrict__ w, __hip_bfloat16* __restrict__ out) {
  int row = blockIdx.x;
  const float* xr = x + (size_t)row * DIM;
  float ss = 0.f;
  for (int i = threadIdx.x; i < DIM; i += 256) { float v = xr[i]; ss += v * v; }
  for (int off = 32; off; off >>= 1) ss += __shfl_xor(ss, off);
  __shared__ float wsum[4];
  if ((threadIdx.x & 63) == 0) wsum[threadIdx.x >> 6] = ss;
  __syncthreads();
  float tot = wsum[0] + wsum[1] + wsum[2] + wsum[3];
  float r = rsqrtf(tot / (float)DIM + 1e-5f);
  __hip_bfloat16* orow = out + (size_t)row * DIM;
  for (int i = threadIdx.x; i < DIM; i += 256)
    orow[i] = __float2bfloat16(w[i] * (xr[i] * r));
}

// ---------------- weight transpose+convert: W[K][N] f32 -> WT[N][K] bf16 ----------------
__global__ __launch_bounds__(256) void k_wt(const float* __restrict__ W,
    __hip_bfloat16* __restrict__ WT, int K, int N) {
  __shared__ __hip_bfloat16 t[64][72];   // [n][k], +8 pad
  int k0 = blockIdx.y * 64, n0 = blockIdx.x * 64;
  int r = threadIdx.x >> 4;          // 0..15
  int c4 = (threadIdx.x & 15) * 4;   // 0..60
#pragma unroll
  for (int i = 0; i < 4; ++i) {
    int k = r + i * 16;
    f32x4 v = *(const f32x4*)(W + (size_t)(k0 + k) * N + n0 + c4);
#pragma unroll
    for (int j = 0; j < 4; ++j) t[c4 + j][k] = __float2bfloat16(v[j]);
  }
  __syncthreads();
  int n = threadIdx.x >> 2, kc = (threadIdx.x & 3) * 16;
  bf16x8* dst = (bf16x8*)(WT + (size_t)(n0 + n) * K + k0 + kc);
  dst[0] = *(const bf16x8*)&t[n][kc];
  dst[1] = *(const bf16x8*)&t[n][kc + 8];
}

// ---------------- big GEMM: 256x256, per-half-K phases, 4-slot LDS ring ----------------
// A bf16 [M][K], BT bf16 [N][K]. Requires M==2048, N%256==0, K%64==0, K>=192.
// Phase = one K=32 half: {12 ds_read | 4 stage gloads | vmcnt | bar | lgkm |
// 32 MFMA | bar}. Staging 3 phases ahead into ring slots not being read.
// LDS half-buffer layout: logical (r,c8) -> line=r>>1, slot=((r&1)*4+c8)^(line&7):
// bijective, staging inst = linear 1024B segment, fragment reads 2-way-free.
// EPI: 0 = store f32, 1 = add into f32, 2 = store bf16
template<int EPI>
__global__ __launch_bounds__(512) void k_gemm256(
    const __hip_bfloat16* __restrict__ A, const __hip_bfloat16* __restrict__ BT,
    void* __restrict__ Cv, int M, int N, int K) {
  __shared__ __hip_bfloat16 AsH[4][128][64];   // 64 KiB (4 ring slots)
  __shared__ __hip_bfloat16 BsH[4][128][64];   // 64 KiB
  const int NH = K >> 5;                       // number of K=32 halves
  int tid = threadIdx.x;
  int bid = blockIdx.x;
  int mt = bid & 7, nt = bid >> 3;             // XCD x owns m-strip x, sweeps n
  int bm = mt << 8, bn = nt << 8;
  int wave = tid >> 6, lane = tid & 63;
  int wm = wave >> 2, wn = wave & 3;           // 2x4 wave grid
  int g = lane >> 4, c = lane & 15;
  f32x4 acc[8][4] = {};

  // staging lane constants: inst (wave,rd) writes segment seg=rd*8+wave =
  // lines seg*8..+7 (rows seg*16..+15). lane L -> line seg*8+(L>>3), slot L&7.
  int pre  = (lane & 7) ^ (lane >> 3);
  int rOff = (lane >> 3) * 2 + (pre >> 2);     // row within 16-row segment
  int cOff = (pre & 3) * 8;                    // col within 32-col half

  auto stageA = [&](int S, int h) {            // 2 insts/thread
#pragma unroll
    for (int rd = 0; rd < 2; ++rd) {
      int seg = rd * 8 + wave;
      gload_lds16(A + (size_t)(bm + seg * 16 + rOff) * K + h * 32 + cOff,
                  &AsH[S][seg * 8 + (lane >> 3)][(lane & 7) * 8]);
    }
  };
  auto stageB = [&](int S, int h) {
#pragma unroll
    for (int rd = 0; rd < 2; ++rd) {
      int seg = rd * 8 + wave;
      gload_lds16(BT + (size_t)(bn + seg * 16 + rOff) * K + h * 32 + cOff,
                  &BsH[S][seg * 8 + (lane >> 3)][(lane & 7) * 8]);
    }
  };

  // prologue: A0,B0,A1,B1,A2 (10 insts); half0 = #1-4 -> vmcnt(6) gates it
  stageA(0, 0); stageB(0, 0);
  stageA(1, 1); stageB(1, 1);
  stageA(2, 2);
  asm volatile("s_waitcnt vmcnt(6)" ::: "memory");
  __builtin_amdgcn_s_barrier();
  FENCE();

  // fragment lane constants
  int lineA = wm * 64 + (c >> 1);                       // + mi*8
  int lineB = wn * 32 + (c >> 1);                       // + ni*8
  int slotE = ((((c & 1) << 2) | g) ^ (c >> 1)) * 8;    // element offset in line

  for (int H = 0; H < NH; ++H) {
    int S = H & 3;
    bf16x8 af[8], bv[4];
#pragma unroll
    for (int mi = 0; mi < 8; ++mi)
      af[mi] = *(const bf16x8*)&AsH[S][lineA + mi * 8][slotE];
#pragma unroll
    for (int ni = 0; ni < 4; ++ni)
      bv[ni] = *(const bf16x8*)&BsH[S][lineB + ni * 8][slotE];
    FENCE();
    // stage: B of half H+2 into slot (H+2)&3, A of half H+3 into slot (H+3)&3.
    // Both slots differ from S (read now) and S+1 (fully staged): safe —
    // slot (H+3)&3 was last read in phase H-1, drained by its trailing barrier.
    if (H + 2 < NH) stageB((H + 2) & 3, H + 2);
    if (H + 3 < NH) stageA((H + 3) & 3, H + 3);
    // gate half H+1 (consumed next phase): insts issued after its last load:
    if (H + 4 <= NH)      { asm volatile("s_waitcnt vmcnt(6)" ::: "memory"); }
    else if (H + 3 == NH) { asm volatile("s_waitcnt vmcnt(4)" ::: "memory"); }
    else if (H + 2 == NH) { asm volatile("s_waitcnt vmcnt(0)" ::: "memory"); }
    __builtin_amdgcn_s_barrier();          // RAW gate: everyone vmcnt'd
    asm volatile("s_waitcnt lgkmcnt(0)" ::: "memory");
    __builtin_amdgcn_sched_barrier(0);
    __builtin_amdgcn_s_setprio(1);
#pragma unroll
    for (int mi = 0; mi < 8; ++mi)
#pragma unroll
      for (int ni = 0; ni < 4; ++ni)
        acc[mi][ni] = __builtin_amdgcn_mfma_f32_16x16x32_bf16(af[mi], bv[ni], acc[mi][ni], 0, 0, 0);
    __builtin_amdgcn_s_setprio(0);
    FENCE();
    __builtin_amdgcn_s_barrier();          // WAR gate: all reads of S done
    FENCE();
  }

  float* Cf = (float*)Cv;
  __hip_bfloat16* Cb = (__hip_bfloat16*)Cv;
  int row0 = bm + wm * 128, col0 = bn + wn * 64;
#pragma unroll
  for (int mi = 0; mi < 8; ++mi)
#pragma unroll
    for (int ni = 0; ni < 4; ++ni)
#pragma unroll
      for (int r = 0; r < 4; ++r) {
        int row = row0 + mi * 16 + g * 4 + r;
        int col = col0 + ni * 16 + c;
        size_t idx = (size_t)row * N + col;
        if (EPI == 0) Cf[idx] = acc[mi][ni][r];
        else if (EPI == 1) Cf[idx] += acc[mi][ni][r];
        else Cb[idx] = __float2bfloat16(acc[mi][ni][r]);
      }
}

// ---------------- 128x128 GEMM, BK=64, counted-vmcnt 2-deep, swizzled LDS ----------------
template<int EPI>
__global__ __launch_bounds__(256) void k_gemm_bt(
    const __hip_bfloat16* __restrict__ A, const __hip_bfloat16* __restrict__ BT,
    void* __restrict__ Cv, int M, int N, int K) {
  __shared__ __hip_bfloat16 As[2][128][64];   // 32 KiB
  __shared__ __hip_bfloat16 Bs[2][128][64];   // 32 KiB
  int nm = M >> 7;
  int bid = blockIdx.x;
  int mt, nt;
  if (nm == 16) {
    int xcd = bid & 7;
    int seq = bid >> 3;
    mt = (xcd << 1) | (seq & 1);
    nt = seq >> 1;
  } else {
    mt = bid % nm;
    nt = bid / nm;
  }
  int bm = mt << 7, bn = nt << 7;
  int tid  = threadIdx.x;
  int wave = tid >> 6, lane = tid & 63;
  int wr = (wave >> 1) * 64, wc = (wave & 1) * 64;
  int g = lane >> 4, c = lane & 15;
  f32x4 acc[4][4] = {};

  auto stage = [&](int buf, int k0) {   // 8 vmem insts/wave
#pragma unroll
    for (int i = 0; i < 4; ++i) {
      int ci = i * 256 + tid;            // 0..1023
      int row = ci >> 3, pc = ci & 7;
      int jl = pc ^ (row & 7);
      gload_lds16(A + (size_t)(bm + row) * K + k0 + jl * 8, &As[buf][row][pc * 8]);
      gload_lds16(BT + (size_t)(bn + row) * K + k0 + jl * 8, &Bs[buf][row][pc * 8]);
    }
  };

  int ntiles = K >> 6;
  stage(0, 0);
  if (ntiles > 1) stage(1, 64);

  for (int t = 0; t < ntiles; ++t) {
    int cur = t & 1;
    if (t + 1 < ntiles) asm volatile("s_waitcnt vmcnt(8)" ::: "memory");
    else                asm volatile("s_waitcnt vmcnt(0)" ::: "memory");
    __builtin_amdgcn_s_barrier();
    FENCE();
    __builtin_amdgcn_sched_barrier(0);
#pragma unroll
    for (int kk = 0; kk < 2; ++kk) {
      bf16x8 af[4], bv[4];
#pragma unroll
      for (int mi = 0; mi < 4; ++mi) {
        int row = wr + mi * 16 + c;
        int ch = (kk * 4 + g) ^ (row & 7);
        af[mi] = *(const bf16x8*)&As[cur][row][ch * 8];
      }
#pragma unroll
      for (int ni = 0; ni < 4; ++ni) {
        int row = wc + ni * 16 + c;
        int ch = (kk * 4 + g) ^ (row & 7);
        bv[ni] = *(const bf16x8*)&Bs[cur][row][ch * 8];
      }
      __builtin_amdgcn_s_setprio(1);
#pragma unroll
      for (int mi = 0; mi < 4; ++mi)
#pragma unroll
        for (int ni = 0; ni < 4; ++ni)
          acc[mi][ni] = __builtin_amdgcn_mfma_f32_16x16x32_bf16(af[mi], bv[ni], acc[mi][ni], 0, 0, 0);
      __builtin_amdgcn_s_setprio(0);
    }
    FENCE();
    __builtin_amdgcn_s_barrier();
    FENCE();
    if (t + 2 < ntiles) stage(cur, (t + 2) << 6);
  }

  float* Cf = (float*)Cv;
  __hip_bfloat16* Cb = (__hip_bfloat16*)Cv;
#pragma unroll
  for (int mi = 0; mi < 4; ++mi)
#pragma unroll
    for (int ni = 0; ni < 4; ++ni)
#pragma unroll
      for (int r = 0; r < 4; ++r) {
        int row = bm + wr + mi * 16 + g * 4 + r;
        int col = bn + wc + ni * 16 + c;
        size_t idx = (size_t)row * N + col;
        if (EPI == 0) Cf[idx] = acc[mi][ni][r];
        else if (EPI == 1) Cf[idx] += acc[mi][ni][r];
        else Cb[idx] = __float2bfloat16(acc[mi][ni][r]);
      }
}

// ---------------- fallback GEMM: B from f32 weights ----------------
template<int EPI>
__global__ __launch_bounds__(256) void k_gemm(
    const __hip_bfloat16* __restrict__ A, const float* __restrict__ Bw,
    void* __restrict__ Cv, int M, int N, int K) {
  __shared__ __hip_bfloat16 As[128][32];
  __shared__ __hip_bfloat16 Bs[128][40];
  int tid  = threadIdx.x;
  int bm = blockIdx.y * 128, bn = blockIdx.x * 128;
  int wave = tid >> 6, lane = tid & 63;
  int wr = (wave >> 1) * 64, wc = (wave & 1) * 64;
  int lrow = lane & 15, lk = (lane >> 4) * 8;
  f32x4 acc[4][4] = {};
  for (int k0 = 0; k0 < K; k0 += 32) {
#pragma unroll
    for (int i = 0; i < 2; ++i) {
      int L = i * 256 + tid;
      int row = L >> 2, koff = (L & 3) * 8;
      gload_lds16(A + (size_t)(bm + row) * K + k0 + koff, &As[row][koff]);
    }
#pragma unroll
    for (int i = 0; i < 4; ++i) {
      int L = i * 256 + tid;
      int kk = L >> 5;
      int c4 = (L & 31) * 4;
      f32x4 v = *(const f32x4*)(Bw + (size_t)(k0 + kk) * N + bn + c4);
#pragma unroll
      for (int j = 0; j < 4; ++j) Bs[c4 + j][kk] = __float2bfloat16(v[j]);
    }
    __syncthreads();
    bf16x8 af[4], bfr[4];
#pragma unroll
    for (int mi = 0; mi < 4; ++mi)
      af[mi] = *(const bf16x8*)(&As[wr + mi * 16 + lrow][lk]);
#pragma unroll
    for (int ni = 0; ni < 4; ++ni)
      bfr[ni] = *(const bf16x8*)(&Bs[wc + ni * 16 + lrow][lk]);
#pragma unroll
    for (int mi = 0; mi < 4; ++mi)
#pragma unroll
      for (int ni = 0; ni < 4; ++ni)
        acc[mi][ni] = __builtin_amdgcn_mfma_f32_16x16x32_bf16(af[mi], bfr[ni], acc[mi][ni], 0, 0, 0);
    __syncthreads();
  }
  float* Cf = (float*)Cv;
  __hip_bfloat16* Cb = (__hip_bfloat16*)Cv;
#pragma unroll
  for (int mi = 0; mi < 4; ++mi)
#pragma unroll
    for (int ni = 0; ni < 4; ++ni)
#pragma unroll
      for (int r = 0; r < 4; ++r) {
        int row = bm + wr + mi * 16 + ((lane >> 4) * 4 + r);
        int col = bn + wc + ni * 16 + (lane & 15);
        size_t idx = (size_t)row * N + col;
        if (EPI == 0) Cf[idx] = acc[mi][ni][r];
        else if (EPI == 1) Cf[idx] += acc[mi][ni][r];
        else Cb[idx] = __float2bfloat16(acc[mi][ni][r]);
      }
}

// ---------------- RoPE + QKV split/reorder (Q pre-scaled, V transposed) ----------------
__global__ __launch_bounds__(256) void k_rope(const float* __restrict__ qkv,
    __hip_bfloat16* __restrict__ qr, __hip_bfloat16* __restrict__ kr,
    __hip_bfloat16* __restrict__ vt) {
  int rowid = blockIdx.x;
  int b = rowid >> 10, s = rowid & (S_LEN - 1);
  const float* src = qkv + (size_t)rowid * 3072;
  const float kInvLog = 0.20503692777f;  // ln(500000)/64
  const float scale = 0.08838834764831845f;  // 1/sqrt(128)
  __shared__ float cs[64], sn[64];
  if (threadIdx.x < 64) {
    float inv = expf(-(float)threadIdx.x * kInvLog);
    float a = (float)s * inv;
    sincosf(a, &sn[threadIdx.x], &cs[threadIdx.x]);
  }
  __syncthreads();
  for (int it = threadIdx.x; it < NHQ * 64; it += 256) {
    int h = it >> 6, i = it & 63;
    float re = src[h * HDIM + i], im = src[h * HDIM + 64 + i];
    size_t dst = ((size_t)(b * NHQ + h) * S_LEN + s) * HDIM;
    qr[dst + 2 * i]     = __float2bfloat16((re * cs[i] - im * sn[i]) * scale);
    qr[dst + 2 * i + 1] = __float2bfloat16((re * sn[i] + im * cs[i]) * scale);
  }
  for (int it = threadIdx.x; it < NHKV * 64; it += 256) {
    int h = it >> 6, i = it & 63;
    float re = src[DIM + h * HDIM + i], im = src[DIM + h * HDIM + 64 + i];
    size_t dst = ((size_t)(b * NHKV + h) * S_LEN + s) * HDIM;
    kr[dst + 2 * i]     = __float2bfloat16(re * cs[i] - im * sn[i]);
    kr[dst + 2 * i + 1] = __float2bfloat16(re * sn[i] + im * cs[i]);
  }
  // V transposed: vt[b][hk][hd][s]
  for (int it = threadIdx.x; it < NHKV * HDIM; it += 256) {
    int h = it >> 7, d = it & 127;
    vt[(((size_t)b * NHKV + h) * HDIM + d) * S_LEN + s] =
        __float2bfloat16(src[DIM + NHKV * HDIM + it]);
  }
}

// ---------------- MFMA flash attention ----------------
__global__ __launch_bounds__(256) void k_attn_mfma(
    const __hip_bfloat16* __restrict__ Q,   // [B][HQ][S][HD]
    const __hip_bfloat16* __restrict__ Kc,  // [B][HKV][S][HD]
    const __hip_bfloat16* __restrict__ VT,  // [B][HKV][HD][S]
    __hip_bfloat16* __restrict__ O) {       // [B*S][2048], col = h*128+d
  __shared__ __hip_bfloat16 plds[4][16][40];
  int wave = threadIdx.x >> 6, lane = threadIdx.x & 63;
  int gw = blockIdx.x * 4 + wave;
  int qt = gw & 63;
  int bh = gw >> 6;
  int b = bh >> 4, h = bh & 15;
  int hk = h >> 2;
  int q0 = qt * 16;
  int g = lane >> 4, c = lane & 15;
  const __hip_bfloat16* Qb = Q + ((size_t)bh * S_LEN + q0) * HDIM;
  const __hip_bfloat16* Kb = Kc + (size_t)(b * NHKV + hk) * S_LEN * HDIM;
  const __hip_bfloat16* Vb = VT + (size_t)(b * NHKV + hk) * S_LEN * HDIM;

  bf16x8 qf[4];
#pragma unroll
  for (int cn = 0; cn < 4; ++cn)
    qf[cn] = *(const bf16x8*)(Qb + (size_t)c * HDIM + cn * 32 + g * 8);

  f32x4 po[8] = {};
  float m[4], l[4];
#pragma unroll
  for (int r = 0; r < 4; ++r) { m[r] = -1e30f; l[r] = 0.f; }

  int kvend = q0 + 16;
  for (int kv0 = 0; kv0 < kvend; kv0 += 32) {
    f32x4 s0 = {}, s1 = {};
#pragma unroll
    for (int cn = 0; cn < 4; ++cn) {
      bf16x8 k0f = *(const bf16x8*)(Kb + (size_t)(kv0 + c) * HDIM + cn * 32 + g * 8);
      bf16x8 k1f = *(const bf16x8*)(Kb + (size_t)(kv0 + 16 + c) * HDIM + cn * 32 + g * 8);
      s0 = __builtin_amdgcn_mfma_f32_16x16x32_bf16(qf[cn], k0f, s0, 0, 0, 0);
      s1 = __builtin_amdgcn_mfma_f32_16x16x32_bf16(qf[cn], k1f, s1, 0, 0, 0);
    }
    if (kv0 + 31 > q0) {
#pragma unroll
      for (int r = 0; r < 4; ++r) {
        int qrow = q0 + g * 4 + r;
        if (kv0 + c > qrow)      s0[r] = -1e30f;
        if (kv0 + 16 + c > qrow) s1[r] = -1e30f;
      }
    }
    float rm[4];
#pragma unroll
    for (int r = 0; r < 4; ++r) rm[r] = fmaxf(s0[r], s1[r]);
#pragma unroll
    for (int off = 1; off < 16; off <<= 1)
#pragma unroll
      for (int r = 0; r < 4; ++r) rm[r] = fmaxf(rm[r], __shfl_xor(rm[r], off));
    float p0[4], p1[4], rs[4];
#pragma unroll
    for (int r = 0; r < 4; ++r) {
      float mn = fmaxf(m[r], rm[r]);
      float corr = __expf(m[r] - mn);
      m[r] = mn;
      p0[r] = __expf(s0[r] - mn);
      p1[r] = __expf(s1[r] - mn);
      rs[r] = p0[r] + p1[r];
      l[r] *= corr;
#pragma unroll
      for (int t = 0; t < 8; ++t) po[t][r] *= corr;
    }
#pragma unroll
    for (int off = 1; off < 16; off <<= 1)
#pragma unroll
      for (int r = 0; r < 4; ++r) rs[r] += __shfl_xor(rs[r], off);
#pragma unroll
    for (int r = 0; r < 4; ++r) l[r] += rs[r];
#pragma unroll
    for (int r = 0; r < 4; ++r) {
      plds[wave][g * 4 + r][c]      = __float2bfloat16(p0[r]);
      plds[wave][g * 4 + r][16 + c] = __float2bfloat16(p1[r]);
    }
    bf16x8 pf = *(const bf16x8*)&plds[wave][c][g * 8];
#pragma unroll
    for (int t = 0; t < 8; ++t) {
      bf16x8 vf = *(const bf16x8*)(Vb + (size_t)(t * 16 + c) * S_LEN + kv0 + g * 8);
      po[t] = __builtin_amdgcn_mfma_f32_16x16x32_bf16(pf, vf, po[t], 0, 0, 0);
    }
  }
  float inv[4];
#pragma unroll
  for (int r = 0; r < 4; ++r) inv[r] = 1.f / l[r];
  __hip_bfloat16* ob = O + ((size_t)(b * S_LEN) + q0) * DIM + h * HDIM;
#pragma unroll
  for (int t = 0; t < 8; ++t)
#pragma unroll
    for (int r = 0; r < 4; ++r)
      ob[(size_t)(g * 4 + r) * DIM + t * 16 + c] = __float2bfloat16(po[t][r] * inv[r]);
}

// ---------------- swiglu (vectorized bf16x8) ----------------
__global__ __launch_bounds__(256) void k_swiglu(const __hip_bfloat16* __restrict__ gu,
    __hip_bfloat16* __restrict__ h) {
  size_t i = (size_t)blockIdx.x * 256 + threadIdx.x;   // over NROWS*PDIM/8
  size_t row = i >> 10, c8 = (i & 1023) * 8;
  const __hip_bfloat16* grow = gu + row * (2 * PDIM);
  bf16x8 gv = *(const bf16x8*)(grow + c8);
  bf16x8 uv = *(const bf16x8*)(grow + PDIM + c8);
  const __hip_bfloat16* gp = (const __hip_bfloat16*)&gv;
  const __hip_bfloat16* up = (const __hip_bfloat16*)&uv;
  __hip_bfloat16 ov[8];
#pragma unroll
  for (int j = 0; j < 8; ++j) {
    float g = __bfloat162float(gp[j]);
    float u = __bfloat162float(up[j]);
    float s = g / (1.f + __expf(-g));
    ov[j] = __float2bfloat16(s * u);
  }
  *(bf16x8*)(h + row * PDIM + c8) = *(const bf16x8*)ov;
}

extern "C" void kernel_launch(void* const* d_in, const int* in_sizes, int n_in,
                              void* d_out, int out_size, void* d_ws, size_t ws_size,
                              hipStream_t stream) {
  const int*   tokens    = (const int*)d_in[0];
  const float* emb       = (const float*)d_in[1];
  const float* w_qkv     = (const float*)d_in[2];
  const float* w_o       = (const float*)d_in[3];
  const float* w_gate_up = (const float*)d_in[4];
  const float* w_down    = (const float*)d_in[5];
  const float* ln_attn   = (const float*)d_in[6];
  const float* ln_ffn    = (const float*)d_in[7];
  const float* ln_f      = (const float*)d_in[8];
  const float* w_lm      = (const float*)d_in[9];
  float* out = (float*)d_out;

  char* ws = (char*)d_ws;
  float* x = (float*)ws;                    ws += (size_t)NROWS * DIM * 4;
  __hip_bfloat16* xn = (__hip_bfloat16*)ws; ws += (size_t)NROWS * DIM * 2;
  float* qkv = (float*)ws;                  ws += (size_t)NROWS * 3072 * 4;
  __hip_bfloat16* qr = (__hip_bfloat16*)ws; ws += (size_t)2 * NHQ * S_LEN * HDIM * 2;
  __hip_bfloat16* kr = (__hip_bfloat16*)ws; ws += (size_t)2 * NHKV * S_LEN * HDIM * 2;
  __hip_bfloat16* vt = (__hip_bfloat16*)ws; ws += (size_t)2 * NHKV * S_LEN * HDIM * 2;
  __hip_bfloat16* ao = (__hip_bfloat16*)ws; ws += (size_t)NROWS * DIM * 2;
  __hip_bfloat16* gu = (__hip_bfloat16*)ws; ws += (size_t)NROWS * 2 * PDIM * 2;
  __hip_bfloat16* hb = (__hip_bfloat16*)ws; ws += (size_t)NROWS * PDIM * 2;
  __hip_bfloat16* wbuf = (__hip_bfloat16*)ws;           // JIT bf16 W^T buffer
  size_t need = (size_t)(ws - (char*)d_ws) + (size_t)VOCAB * DIM * 2;
  bool bf16w = ws_size >= need;

  k_embed<<<NROWS, 256, 0, stream>>>(tokens, emb, x);

  for (int l = 0; l < NLAYER; ++l) {
    k_rmsnorm<<<NROWS, 256, 0, stream>>>(x, ln_attn + (size_t)l * DIM, xn);
    if (bf16w) {
      k_wt<<<dim3(3072 / 64, DIM / 64), 256, 0, stream>>>(
          w_qkv + (size_t)l * DIM * 3072, wbuf, DIM, 3072);
      k_gemm_bt<0><<<(NROWS / 128) * (3072 / 128), 256, 0, stream>>>(
          xn, wbuf, qkv, NROWS, 3072, DIM);
    } else {
      k_gemm<0><<<dim3(3072 / 128, NROWS / 128), 256, 0, stream>>>(
          xn, w_qkv + (size_t)l * DIM * 3072, qkv, NROWS, 3072, DIM);
    }
    k_rope<<<NROWS, 256, 0, stream>>>(qkv, qr, kr, vt);
    k_attn_mfma<<<(2 * NHQ * (S_LEN / 16)) / 4, 256, 0, stream>>>(qr, kr, vt, ao);
    if (bf16w) {
      k_wt<<<dim3(DIM / 64, DIM / 64), 256, 0, stream>>>(
          w_o + (size_t)l * DIM * DIM, wbuf, DIM, DIM);
      k_gemm_bt<1><<<(NROWS / 128) * (DIM / 128), 256, 0, stream>>>(
          ao, wbuf, x, NROWS, DIM, DIM);
    } else {
      k_gemm<1><<<dim3(DIM / 128, NROWS / 128), 256, 0, stream>>>(
          ao, w_o + (size_t)l * DIM * DIM, x, NROWS, DIM, DIM);
    }
    k_rmsnorm<<<NROWS, 256, 0, stream>>>(x, ln_ffn + (size_t)l * DIM, xn);
    if (bf16w) {
      k_wt<<<dim3(2 * PDIM / 64, DIM / 64), 256, 0, stream>>>(
          w_gate_up + (size_t)l * DIM * 2 * PDIM, wbuf, DIM, 2 * PDIM);
      k_gemm256<2><<<8 * (2 * PDIM / 256), 512, 0, stream>>>(
          xn, wbuf, gu, NROWS, 2 * PDIM, DIM);
    } else {
      k_gemm<2><<<dim3(2 * PDIM / 128, NROWS / 128), 256, 0, stream>>>(
          xn, w_gate_up + (size_t)l * DIM * 2 * PDIM, gu, NROWS, 2 * PDIM, DIM);
    }
    k_swiglu<<<(NROWS * PDIM / 8) / 256, 256, 0, stream>>>(gu, hb);
    if (bf16w) {
      k_wt<<<dim3(DIM / 64, PDIM / 64), 256, 0, stream>>>(
          w_down + (size_t)l * PDIM * DIM, wbuf, PDIM, DIM);
      k_gemm_bt<1><<<(NROWS / 128) * (DIM / 128), 256, 0, stream>>>(
          hb, wbuf, x, NROWS, DIM, PDIM);
    } else {
      k_gemm<1><<<dim3(DIM / 128, NROWS / 128), 256, 0, stream>>>(
          hb, w_down + (size_t)l * PDIM * DIM, x, NROWS, DIM, PDIM);
    }
  }

  k_rmsnorm<<<NROWS, 256, 0, stream>>>(x, ln_f, xn);
  if (bf16w) {
    k_wt<<<dim3(VOCAB / 64, DIM / 64), 256, 0, stream>>>(w_lm, wbuf, DIM, VOCAB);
    k_gemm256<0><<<8 * (VOCAB / 256), 512, 0, stream>>>(
        xn, wbuf, out, NROWS, VOCAB, DIM);
  } else {
    k_gemm<0><<<dim3(VOCAB / 128, NROWS / 128), 256, 0, stream>>>(
        xn, w_lm, out, NROWS, VOCAB, DIM);
  }
}